// Round 1
// baseline (1824.373 us; speedup 1.0000x reference)
//
#include <hip/hip_runtime.h>

#define N_NODES 50000
#define N_EDGES 800000
#define D 128

// ---------------------------------------------------------------------------
// deg[i] = 1 (self-loop)
__global__ void k_init_deg(float* __restrict__ deg) {
    int i = blockIdx.x * blockDim.x + threadIdx.x;
    if (i < N_NODES) deg[i] = 1.0f;
}

// deg[dst[e]] += 1
__global__ void k_accum_deg(const int* __restrict__ dst, float* __restrict__ deg) {
    int e = blockIdx.x * blockDim.x + threadIdx.x;
    if (e < N_EDGES) atomicAdd(&deg[dst[e]], 1.0f);
}

// deg -> rsqrt(deg)  (deg >= 1 always, so no zero guard needed)
__global__ void k_rsqrt(float* __restrict__ deg) {
    int i = blockIdx.x * blockDim.x + threadIdx.x;
    if (i < N_NODES) deg[i] = rsqrtf(deg[i]);
}

// ---------------------------------------------------------------------------
// xw[row] = x[row] @ Wc    one block (128 threads) per row
__global__ void k_gemm_xw(const float* __restrict__ x, const float* __restrict__ Wc,
                          float* __restrict__ xw) {
    __shared__ float xr[D];
    const int row = blockIdx.x;
    const int j = threadIdx.x;
    xr[j] = x[(long)row * D + j];
    __syncthreads();
    float acc = 0.0f;
#pragma unroll 16
    for (int k = 0; k < D; ++k) acc += xr[k] * Wc[k * D + j];
    xw[(long)row * D + j] = acc;
}

// ---------------------------------------------------------------------------
// agg[dst[e]] += xw[src[e]] * dinv[src]*dinv[dst]   (float4 chunks, atomics)
// one thread per (edge, float4-chunk): 32 chunks per edge
__global__ void k_scatter(const int* __restrict__ src, const int* __restrict__ dst,
                          const float* __restrict__ dinv, const float* __restrict__ xw,
                          float* __restrict__ agg) {
    long gid = (long)blockIdx.x * blockDim.x + threadIdx.x;
    int e = (int)(gid >> 5);
    int c = (int)(gid & 31);
    if (e >= N_EDGES) return;
    const int s = src[e];
    const int d = dst[e];
    const float norm = dinv[s] * dinv[d];
    const float4 v = ((const float4*)(xw + (long)s * D))[c];
    float* a = agg + (long)d * D + c * 4;
    atomicAdd(a + 0, v.x * norm);
    atomicAdd(a + 1, v.y * norm);
    atomicAdd(a + 2, v.z * norm);
    atomicAdd(a + 3, v.w * norm);
}

// ---------------------------------------------------------------------------
// per row:
//   h[j]   = agg[row][j] + xw[row][j]*dinv[row]^2 + bc[j]       (self-loop folded in)
//   out[j] = h[j] + sum_k x[row][k]*W0[k][j] + (h[k]-x[row][k])*Wt[k][j]
__global__ void k_finalize(const float* __restrict__ x, const float* __restrict__ agg,
                           const float* __restrict__ xw, const float* __restrict__ dinv,
                           const float* __restrict__ bc, const float* __restrict__ W0,
                           const float* __restrict__ Wt, float* __restrict__ out) {
    __shared__ float xr[D];
    __shared__ float hr[D];  // h - x
    const int row = blockIdx.x;
    const int j = threadIdx.x;
    const float di = dinv[row];
    const float xv = x[(long)row * D + j];
    const float hv = agg[(long)row * D + j] + xw[(long)row * D + j] * di * di + bc[j];
    xr[j] = xv;
    hr[j] = hv - xv;
    __syncthreads();
    float acc = hv;
#pragma unroll 16
    for (int k = 0; k < D; ++k) acc += xr[k] * W0[k * D + j] + hr[k] * Wt[k * D + j];
    out[(long)row * D + j] = acc;
}

// ---------------------------------------------------------------------------
extern "C" void kernel_launch(void* const* d_in, const int* in_sizes, int n_in,
                              void* d_out, int out_size, void* d_ws, size_t ws_size,
                              hipStream_t stream) {
    const float* x  = (const float*)d_in[0];
    const int*   ei = (const int*)d_in[1];      // [2, E] flat: row0=src, row1=dst
    const float* Wc = (const float*)d_in[2];
    const float* bc = (const float*)d_in[3];
    const float* W0 = (const float*)d_in[4];
    const float* Wt = (const float*)d_in[5];
    float* out = (float*)d_out;

    const int* src = ei;
    const int* dst = ei + N_EDGES;

    // workspace layout: xw [N*D] | agg [N*D] | deg [N]
    float* xw  = (float*)d_ws;
    float* agg = xw + (long)N_NODES * D;
    float* deg = agg + (long)N_NODES * D;

    hipMemsetAsync(agg, 0, (size_t)N_NODES * D * sizeof(float), stream);

    k_init_deg<<<(N_NODES + 255) / 256, 256, 0, stream>>>(deg);
    k_accum_deg<<<(N_EDGES + 255) / 256, 256, 0, stream>>>(dst, deg);
    k_rsqrt<<<(N_NODES + 255) / 256, 256, 0, stream>>>(deg);

    k_gemm_xw<<<N_NODES, D, 0, stream>>>(x, Wc, xw);

    const long scatter_threads = (long)N_EDGES * 32;
    k_scatter<<<(int)((scatter_threads + 255) / 256), 256, 0, stream>>>(src, dst, deg, xw, agg);

    k_finalize<<<N_NODES, D, 0, stream>>>(x, agg, xw, deg, bc, W0, Wt, out);
}

// Round 2
// 693.185 us; speedup vs baseline: 2.6319x; 2.6319x over previous
//
#include <hip/hip_runtime.h>

#define N_NODES 50000
#define N_EDGES 800000
#define D 128
#define SCAN_T 1024

// ---------------------------------------------------------------------------
// cnt[dst[e]] += 1   (int histogram; cnt pre-zeroed by memset)
__global__ void k_hist(const int* __restrict__ dst, int* __restrict__ cnt) {
    int e = blockIdx.x * blockDim.x + threadIdx.x;
    if (e < N_EDGES) atomicAdd(&cnt[dst[e]], 1);
}

// dinv[i] = rsqrt(cnt[i] + 1)   (+1 = self loop)
__global__ void k_dinv(const int* __restrict__ cnt, float* __restrict__ dinv) {
    int i = blockIdx.x * blockDim.x + threadIdx.x;
    if (i < N_NODES) dinv[i] = rsqrtf((float)cnt[i] + 1.0f);
}

// single-block exclusive scan of cnt[N_NODES] -> row_start[N_NODES]
__global__ void k_scan(const int* __restrict__ cnt, int* __restrict__ row_start) {
    __shared__ int part[SCAN_T];
    const int t = threadIdx.x;
    const int CH = (N_NODES + SCAN_T - 1) / SCAN_T;  // 49
    const int base = t * CH;
    int s = 0;
    for (int i = 0; i < CH; ++i) {
        int idx = base + i;
        if (idx < N_NODES) s += cnt[idx];
    }
    part[t] = s;
    __syncthreads();
    for (int off = 1; off < SCAN_T; off <<= 1) {
        int v = (t >= off) ? part[t - off] : 0;
        __syncthreads();
        part[t] += v;
        __syncthreads();
    }
    int run = (t > 0) ? part[t - 1] : 0;  // exclusive prefix of this thread's chunk
    for (int i = 0; i < CH; ++i) {
        int idx = base + i;
        if (idx < N_NODES) {
            row_start[idx] = run;
            run += cnt[idx];
        }
    }
}

// esrc[row_start[dst] + cursor[dst]++] = src   (cursor pre-zeroed)
__global__ void k_reorder(const int* __restrict__ src, const int* __restrict__ dst,
                          const int* __restrict__ row_start, int* __restrict__ cursor,
                          int* __restrict__ esrc) {
    int e = blockIdx.x * blockDim.x + threadIdx.x;
    if (e >= N_EDGES) return;
    int d = dst[e];
    int pos = row_start[d] + atomicAdd(&cursor[d], 1);
    esrc[pos] = src[e];
}

// ---------------------------------------------------------------------------
// xs[row] = (x[row] @ Wc) * dinv[row]     one block (128 threads) per row
__global__ void k_gemm_xs(const float* __restrict__ x, const float* __restrict__ Wc,
                          const float* __restrict__ dinv, float* __restrict__ xs) {
    __shared__ float xr[D];
    const int row = blockIdx.x;
    const int j = threadIdx.x;
    xr[j] = x[(long)row * D + j];
    __syncthreads();
    float acc = 0.0f;
#pragma unroll 16
    for (int k = 0; k < D; ++k) acc += xr[k] * Wc[k * D + j];
    xs[(long)row * D + j] = acc * dinv[row];
}

// ---------------------------------------------------------------------------
// Fused gather-aggregate + epilogue. One block (128 threads) per node.
//   acc_j = xs[row][j] + sum_{e in CSR row} xs[esrc[e]][j]
//   h_j   = acc_j * dinv[row] + bc[j]
//   out_j = h_j + sum_k x[row][k]*W0[k][j] + (h[k]-x[row][k])*Wt[k][j]
__global__ void k_fused(const float* __restrict__ x, const float* __restrict__ xs,
                        const int* __restrict__ row_start, const int* __restrict__ cnt,
                        const int* __restrict__ esrc, const float* __restrict__ dinv,
                        const float* __restrict__ bc, const float* __restrict__ W0,
                        const float* __restrict__ Wt, float* __restrict__ out) {
    __shared__ int slds[D];
    __shared__ float xr[D];
    __shared__ float hr[D];  // h - x
    const int row = blockIdx.x;
    const int j = threadIdx.x;
    const int begin = row_start[row];
    const int end = begin + cnt[row];

    float acc = xs[(long)row * D + j];  // self-loop term
    for (int base = begin; base < end; base += D) {
        const int m = min(D, end - base);
        __syncthreads();
        if (j < m) slds[j] = esrc[base + j];
        __syncthreads();
        for (int i = 0; i < m; ++i) acc += xs[(long)slds[i] * D + j];
    }

    const float hv = acc * dinv[row] + bc[j];
    const float xv = x[(long)row * D + j];
    xr[j] = xv;
    hr[j] = hv - xv;
    __syncthreads();
    float o = hv;
#pragma unroll 16
    for (int k = 0; k < D; ++k) o += xr[k] * W0[k * D + j] + hr[k] * Wt[k * D + j];
    out[(long)row * D + j] = o;
}

// ---------------------------------------------------------------------------
extern "C" void kernel_launch(void* const* d_in, const int* in_sizes, int n_in,
                              void* d_out, int out_size, void* d_ws, size_t ws_size,
                              hipStream_t stream) {
    const float* x  = (const float*)d_in[0];
    const int*   ei = (const int*)d_in[1];  // [2, E] flat: row0=src, row1=dst
    const float* Wc = (const float*)d_in[2];
    const float* bc = (const float*)d_in[3];
    const float* W0 = (const float*)d_in[4];
    const float* Wt = (const float*)d_in[5];
    float* out = (float*)d_out;

    const int* src = ei;
    const int* dst = ei + N_EDGES;

    // workspace layout (floats/ints are both 4 B):
    //   xs [N*D] | cnt [N] | cursor [N] | row_start [N] | dinv [N] | esrc [E]
    float* xs        = (float*)d_ws;
    int*   cnt       = (int*)(xs + (long)N_NODES * D);
    int*   cursor    = cnt + N_NODES;
    int*   row_start = cursor + N_NODES;
    float* dinv      = (float*)(row_start + N_NODES);
    int*   esrc      = (int*)(dinv + N_NODES);

    // zero cnt + cursor in one memset (adjacent)
    hipMemsetAsync(cnt, 0, 2 * (size_t)N_NODES * sizeof(int), stream);

    k_hist<<<(N_EDGES + 255) / 256, 256, 0, stream>>>(dst, cnt);
    k_scan<<<1, SCAN_T, 0, stream>>>(cnt, row_start);
    k_dinv<<<(N_NODES + 255) / 256, 256, 0, stream>>>(cnt, dinv);
    k_reorder<<<(N_EDGES + 255) / 256, 256, 0, stream>>>(src, dst, row_start, cursor, esrc);

    k_gemm_xs<<<N_NODES, D, 0, stream>>>(x, Wc, dinv, xs);

    k_fused<<<N_NODES, D, 0, stream>>>(x, xs, row_start, cnt, esrc, dinv, bc, W0, Wt, out);
}

// Round 3
// 436.617 us; speedup vs baseline: 4.1784x; 1.5876x over previous
//
#include <hip/hip_runtime.h>

#define N_NODES 50000
#define N_EDGES 800000
#define D 128
#define SCAN_T 1024
#define OUT_GRID 768

// ---------------------------------------------------------------------------
// cnt[dst[e]] += 1   (int histogram; cnt pre-zeroed by memset)
__global__ void k_hist(const int* __restrict__ dst, int* __restrict__ cnt) {
    int e = blockIdx.x * blockDim.x + threadIdx.x;
    if (e < N_EDGES) atomicAdd(&cnt[dst[e]], 1);
}

// dinv[i] = rsqrt(cnt[i] + 1)   (+1 = self loop)
__global__ void k_dinv(const int* __restrict__ cnt, float* __restrict__ dinv) {
    int i = blockIdx.x * blockDim.x + threadIdx.x;
    if (i < N_NODES) dinv[i] = rsqrtf((float)cnt[i] + 1.0f);
}

// single-block exclusive scan of cnt[N_NODES] -> row_start[N_NODES]
__global__ void k_scan(const int* __restrict__ cnt, int* __restrict__ row_start) {
    __shared__ int part[SCAN_T];
    const int t = threadIdx.x;
    const int CH = (N_NODES + SCAN_T - 1) / SCAN_T;  // 49
    const int base = t * CH;
    int s = 0;
    for (int i = 0; i < CH; ++i) {
        int idx = base + i;
        if (idx < N_NODES) s += cnt[idx];
    }
    part[t] = s;
    __syncthreads();
    for (int off = 1; off < SCAN_T; off <<= 1) {
        int v = (t >= off) ? part[t - off] : 0;
        __syncthreads();
        part[t] += v;
        __syncthreads();
    }
    int run = (t > 0) ? part[t - 1] : 0;
    for (int i = 0; i < CH; ++i) {
        int idx = base + i;
        if (idx < N_NODES) {
            row_start[idx] = run;
            run += cnt[idx];
        }
    }
}

// esrc[row_start[dst] + cursor[dst]++] = src   (cursor pre-zeroed)
__global__ void k_reorder(const int* __restrict__ src, const int* __restrict__ dst,
                          const int* __restrict__ row_start, int* __restrict__ cursor,
                          int* __restrict__ esrc) {
    int e = blockIdx.x * blockDim.x + threadIdx.x;
    if (e >= N_EDGES) return;
    int d = dst[e];
    int pos = row_start[d] + atomicAdd(&cursor[d], 1);
    esrc[pos] = src[e];
}

// ---------------------------------------------------------------------------
// Wa = Wc + Wc@Wt,  Wb = W0 - Wt      (128 blocks x 128 threads)
__global__ void k_wprep(const float* __restrict__ Wc, const float* __restrict__ W0,
                        const float* __restrict__ Wt, float* __restrict__ Wa,
                        float* __restrict__ Wb) {
    __shared__ float wr[D];
    const int i = blockIdx.x, j = threadIdx.x;
    wr[j] = Wc[i * D + j];
    __syncthreads();
    float acc = wr[j];
#pragma unroll 16
    for (int k = 0; k < D; ++k) acc += wr[k] * Wt[k * D + j];
    Wa[i * D + j] = acc;
    Wb[i * D + j] = W0[i * D + j] - Wt[i * D + j];
}

// bv = bc + bc@Wt    (1 block x 128 threads)
__global__ void k_bprep(const float* __restrict__ bc, const float* __restrict__ Wt,
                        float* __restrict__ bv) {
    const int j = threadIdx.x;
    float acc = bc[j];
#pragma unroll 16
    for (int k = 0; k < D; ++k) acc += bc[k] * Wt[k * D + j];
    bv[j] = acc;
}

// ---------------------------------------------------------------------------
// g[row] = dinv[row] * ( sum_e dinv[src_e]*x[src_e] + dinv[row]*x[row] )
// one node per 256-thread block: threads = 32 col-quads (c) x 8 edge-slots (s)
__global__ __launch_bounds__(256) void k_gather(const float* __restrict__ x,
                                                const int* __restrict__ row_start,
                                                const int* __restrict__ cnt,
                                                const int* __restrict__ esrc,
                                                const float* __restrict__ dinv,
                                                float* __restrict__ g) {
    const int row = blockIdx.x;
    const int t = threadIdx.x;
    const int c = t & 31;
    const int s = t >> 5;
    const int begin = row_start[row];
    const int end = begin + cnt[row];
    const float4* x4 = (const float4*)x;

    float4 acc = {0.f, 0.f, 0.f, 0.f};
    int i = begin + s;
    while (i + 8 < end) {  // two edges per iter: i, i+8
        const int a0 = esrc[i];
        const int a1 = esrc[i + 8];
        const float n0 = dinv[a0];
        const float n1 = dinv[a1];
        const float4 v0 = x4[a0 * 32 + c];
        const float4 v1 = x4[a1 * 32 + c];
        acc.x += n0 * v0.x; acc.y += n0 * v0.y; acc.z += n0 * v0.z; acc.w += n0 * v0.w;
        acc.x += n1 * v1.x; acc.y += n1 * v1.y; acc.z += n1 * v1.z; acc.w += n1 * v1.w;
        i += 16;
    }
    if (i < end) {
        const int a0 = esrc[i];
        const float n0 = dinv[a0];
        const float4 v0 = x4[a0 * 32 + c];
        acc.x += n0 * v0.x; acc.y += n0 * v0.y; acc.z += n0 * v0.z; acc.w += n0 * v0.w;
    }

    __shared__ float4 red[8][32];
    red[s][c] = acc;
    __syncthreads();
    if (s == 0) {
        const float di = dinv[row];
        const float4 xself = x4[row * 32 + c];
        float4 tot = red[0][c];
#pragma unroll
        for (int q = 1; q < 8; ++q) {
            float4 r = red[q][c];
            tot.x += r.x; tot.y += r.y; tot.z += r.z; tot.w += r.w;
        }
        tot.x = di * (tot.x + di * xself.x);
        tot.y = di * (tot.y + di * xself.y);
        tot.z = di * (tot.z + di * xself.z);
        tot.w = di * (tot.w + di * xself.w);
        ((float4*)g)[row * 32 + c] = tot;
    }
}

// ---------------------------------------------------------------------------
// out[row] = g[row]@Wa + x[row]@Wb + bv
// Register-cached weights: thread (c = t&31, s = t>>5) holds Wa/Wb for
// k in [16s,16s+16), cols [4c,4c+4). Rows looped grid-stride; W read once.
__global__ __launch_bounds__(256) void k_out(const float* __restrict__ g,
                                             const float* __restrict__ x,
                                             const float* __restrict__ Wa,
                                             const float* __restrict__ Wb,
                                             const float* __restrict__ bv,
                                             float* __restrict__ out) {
    const int t = threadIdx.x;
    const int c = t & 31;
    const int s = t >> 5;
    const float4* Wa4 = (const float4*)Wa;
    const float4* Wb4 = (const float4*)Wb;
    const float4* g4 = (const float4*)g;
    const float4* x4 = (const float4*)x;

    float4 wa[16], wb[16];
#pragma unroll
    for (int i = 0; i < 16; ++i) {
        const int k = s * 16 + i;
        wa[i] = Wa4[k * 32 + c];
        wb[i] = Wb4[k * 32 + c];
    }
    const float4 bvv = ((const float4*)bv)[c];

    __shared__ float gl[D];
    __shared__ float xl[D];
    __shared__ float4 red[8][32];

    // software pipeline: prefetch first row
    float4 gst = {0, 0, 0, 0}, xst = {0, 0, 0, 0};
    int row = blockIdx.x;
    if (row < N_NODES) {
        if (s == 0) gst = g4[row * 32 + c];
        else if (s == 1) xst = x4[row * 32 + c];
    }
    for (; row < N_NODES; row += gridDim.x) {
        __syncthreads();  // previous iteration's readers done
        if (s == 0) ((float4*)gl)[c] = gst;
        else if (s == 1) ((float4*)xl)[c] = xst;
        __syncthreads();
        const int nrow = row + gridDim.x;
        if (nrow < N_NODES) {
            if (s == 0) gst = g4[nrow * 32 + c];
            else if (s == 1) xst = x4[nrow * 32 + c];
        }
        float4 o = {0.f, 0.f, 0.f, 0.f};
#pragma unroll
        for (int i = 0; i < 16; ++i) {
            const int k = s * 16 + i;
            const float gk = gl[k];
            const float xk = xl[k];
            o.x += gk * wa[i].x + xk * wb[i].x;
            o.y += gk * wa[i].y + xk * wb[i].y;
            o.z += gk * wa[i].z + xk * wb[i].z;
            o.w += gk * wa[i].w + xk * wb[i].w;
        }
        red[s][c] = o;
        __syncthreads();
        if (s == 0) {
            float4 tot = bvv;
#pragma unroll
            for (int q = 0; q < 8; ++q) {
                float4 r = red[q][c];
                tot.x += r.x; tot.y += r.y; tot.z += r.z; tot.w += r.w;
            }
            ((float4*)out)[row * 32 + c] = tot;
        }
    }
}

// ---------------------------------------------------------------------------
extern "C" void kernel_launch(void* const* d_in, const int* in_sizes, int n_in,
                              void* d_out, int out_size, void* d_ws, size_t ws_size,
                              hipStream_t stream) {
    const float* x  = (const float*)d_in[0];
    const int*   ei = (const int*)d_in[1];  // [2, E] flat: row0=src, row1=dst
    const float* Wc = (const float*)d_in[2];
    const float* bc = (const float*)d_in[3];
    const float* W0 = (const float*)d_in[4];
    const float* Wt = (const float*)d_in[5];
    float* out = (float*)d_out;

    const int* src = ei;
    const int* dst = ei + N_EDGES;

    // workspace layout (4 B elems):
    //   g [N*D] | cnt [N] | cursor [N] | row_start [N] | dinv [N] |
    //   esrc [E] | Wa [D*D] | Wb [D*D] | bv [D]
    float* g         = (float*)d_ws;
    int*   cnt       = (int*)(g + (long)N_NODES * D);
    int*   cursor    = cnt + N_NODES;
    int*   row_start = cursor + N_NODES;
    float* dinv      = (float*)(row_start + N_NODES);
    int*   esrc      = (int*)(dinv + N_NODES);
    float* Wa        = (float*)(esrc + N_EDGES);
    float* Wb        = Wa + D * D;
    float* bv        = Wb + D * D;

    hipMemsetAsync(cnt, 0, 2 * (size_t)N_NODES * sizeof(int), stream);

    k_hist<<<(N_EDGES + 255) / 256, 256, 0, stream>>>(dst, cnt);
    k_scan<<<1, SCAN_T, 0, stream>>>(cnt, row_start);
    k_dinv<<<(N_NODES + 255) / 256, 256, 0, stream>>>(cnt, dinv);
    k_reorder<<<(N_EDGES + 255) / 256, 256, 0, stream>>>(src, dst, row_start, cursor, esrc);

    k_wprep<<<D, D, 0, stream>>>(Wc, W0, Wt, Wa, Wb);
    k_bprep<<<1, D, 0, stream>>>(bc, Wt, bv);

    k_gather<<<N_NODES, 256, 0, stream>>>(x, row_start, cnt, esrc, dinv, g);
    k_out<<<OUT_GRID, 256, 0, stream>>>(g, x, Wa, Wb, bv, out);
}

// Round 4
// 339.750 us; speedup vs baseline: 5.3698x; 1.2851x over previous
//
#include <hip/hip_runtime.h>

#define N_NODES 50000
#define N_EDGES 800000
#define D 128
#define SCAN_T 1024

typedef __attribute__((ext_vector_type(8))) short short8;
typedef __attribute__((ext_vector_type(4))) float f32x4;

// round-to-nearest-even f32 -> bf16 (as ushort)
__device__ __forceinline__ unsigned short f2bf(float f) {
    unsigned int u = __builtin_bit_cast(unsigned int, f);
    u += 0x7FFFu + ((u >> 16) & 1u);
    return (unsigned short)(u >> 16);
}

// ---------------------------------------------------------------------------
// cnt[dst[e]] += 1   (int histogram; cnt pre-zeroed by memset)
__global__ void k_hist(const int* __restrict__ dst, int* __restrict__ cnt) {
    int e = blockIdx.x * blockDim.x + threadIdx.x;
    if (e < N_EDGES) atomicAdd(&cnt[dst[e]], 1);
}

// dinv[i] = rsqrt(cnt[i] + 1)   (+1 = self loop)
__global__ void k_dinv(const int* __restrict__ cnt, float* __restrict__ dinv) {
    int i = blockIdx.x * blockDim.x + threadIdx.x;
    if (i < N_NODES) dinv[i] = rsqrtf((float)cnt[i] + 1.0f);
}

// single-block exclusive scan of cnt[N_NODES] -> row_start[N_NODES]
__global__ void k_scan(const int* __restrict__ cnt, int* __restrict__ row_start) {
    __shared__ int part[SCAN_T];
    const int t = threadIdx.x;
    const int CH = (N_NODES + SCAN_T - 1) / SCAN_T;  // 49
    const int base = t * CH;
    int s = 0;
    for (int i = 0; i < CH; ++i) {
        int idx = base + i;
        if (idx < N_NODES) s += cnt[idx];
    }
    part[t] = s;
    __syncthreads();
    for (int off = 1; off < SCAN_T; off <<= 1) {
        int v = (t >= off) ? part[t - off] : 0;
        __syncthreads();
        part[t] += v;
        __syncthreads();
    }
    int run = (t > 0) ? part[t - 1] : 0;
    for (int i = 0; i < CH; ++i) {
        int idx = base + i;
        if (idx < N_NODES) {
            row_start[idx] = run;
            run += cnt[idx];
        }
    }
}

// esrc[row_start[dst] + cursor[dst]++] = src   (cursor pre-zeroed)
__global__ void k_reorder(const int* __restrict__ src, const int* __restrict__ dst,
                          const int* __restrict__ row_start, int* __restrict__ cursor,
                          int* __restrict__ esrc) {
    int e = blockIdx.x * blockDim.x + threadIdx.x;
    if (e >= N_EDGES) return;
    int d = dst[e];
    int pos = row_start[d] + atomicAdd(&cursor[d], 1);
    esrc[pos] = src[e];
}

// ---------------------------------------------------------------------------
// Wa = Wc + Wc@Wt,  Wb = W0 - Wt      (128 blocks x 128 threads, f32)
__global__ void k_wprep(const float* __restrict__ Wc, const float* __restrict__ W0,
                        const float* __restrict__ Wt, float* __restrict__ Wa,
                        float* __restrict__ Wb) {
    __shared__ float wr[D];
    const int i = blockIdx.x, j = threadIdx.x;
    wr[j] = Wc[i * D + j];
    __syncthreads();
    float acc = wr[j];
#pragma unroll 16
    for (int k = 0; k < D; ++k) acc += wr[k] * Wt[k * D + j];
    Wa[i * D + j] = acc;
    Wb[i * D + j] = W0[i * D + j] - Wt[i * D + j];
}

// bv = bc + bc@Wt    (1 block x 128 threads, f32)
__global__ void k_bprep(const float* __restrict__ bc, const float* __restrict__ Wt,
                        float* __restrict__ bv) {
    const int j = threadIdx.x;
    float acc = bc[j];
#pragma unroll 16
    for (int k = 0; k < D; ++k) acc += bc[k] * Wt[k * D + j];
    bv[j] = acc;
}

// Pack Wab = [Wa; Wb] (256 x 128) into bf16 B-fragment order for 16x16x32:
// Wp[((step*8 + tile)*64 + lane)*8 + j] = Wab[step*32 + (lane>>4)*8 + j][tile*16 + (lane&15)]
// 4096 threads, each writes one 16 B fragment slice.
__global__ void k_wpack(const float* __restrict__ Wa, const float* __restrict__ Wb,
                        unsigned short* __restrict__ Wp) {
    const int id = blockIdx.x * blockDim.x + threadIdx.x;  // 0..4095
    const int lane = id & 63;
    const int tile = (id >> 6) & 7;
    const int step = id >> 9;
    const int n = tile * 16 + (lane & 15);
    const int kbase = step * 32 + (lane >> 4) * 8;
    unsigned short v[8];
#pragma unroll
    for (int j = 0; j < 8; ++j) {
        const int k = kbase + j;
        const float f = (k < D) ? Wa[k * D + n] : Wb[(k - D) * D + n];
        v[j] = f2bf(f);
    }
    *(uint4*)(Wp + (long)id * 8) = *(uint4*)v;
}

// ---------------------------------------------------------------------------
// Gather: one 64-lane wave per node (4 nodes / 256-thread block).
//   g[node] = dinv[node] * ( sum_e dinv[src_e]*x[src_e] + dinv[node]*x[node] )
// Writes bf16: gx[node][0:128] = g, gx[node][128:256] = x  (A matrix for k_mm).
__global__ __launch_bounds__(256) void k_gather(const float* __restrict__ x,
                                                const int* __restrict__ row_start,
                                                const int* __restrict__ cnt,
                                                const int* __restrict__ esrc,
                                                const float* __restrict__ dinv,
                                                unsigned short* __restrict__ gx) {
    const int node = blockIdx.x * 4 + (threadIdx.x >> 6);
    const int lane = threadIdx.x & 63;
    const int c = lane & 31;   // float4 column chunk
    const int s = lane >> 5;   // edge slot 0/1
    const int begin = row_start[node];
    const int end = begin + cnt[node];
    const float4* x4 = (const float4*)x;

    float4 acc = {0.f, 0.f, 0.f, 0.f};
    int i = begin + s;
    for (; i + 2 < end; i += 4) {  // two edges in flight per slot
        const int a0 = esrc[i];
        const int a1 = esrc[i + 2];
        const float n0 = dinv[a0];
        const float n1 = dinv[a1];
        const float4 v0 = x4[(long)a0 * 32 + c];
        const float4 v1 = x4[(long)a1 * 32 + c];
        acc.x += n0 * v0.x; acc.y += n0 * v0.y; acc.z += n0 * v0.z; acc.w += n0 * v0.w;
        acc.x += n1 * v1.x; acc.y += n1 * v1.y; acc.z += n1 * v1.z; acc.w += n1 * v1.w;
    }
    if (i < end) {
        const int a0 = esrc[i];
        const float n0 = dinv[a0];
        const float4 v0 = x4[(long)a0 * 32 + c];
        acc.x += n0 * v0.x; acc.y += n0 * v0.y; acc.z += n0 * v0.z; acc.w += n0 * v0.w;
    }

    // combine the two slots (partner lane differs only in bit 5)
    acc.x += __shfl_xor(acc.x, 32);
    acc.y += __shfl_xor(acc.y, 32);
    acc.z += __shfl_xor(acc.z, 32);
    acc.w += __shfl_xor(acc.w, 32);

    if (s == 0) {
        const float di = dinv[node];
        const float4 xs = x4[(long)node * 32 + c];
        ushort4 gv, xv;
        gv.x = f2bf(di * (acc.x + di * xs.x));
        gv.y = f2bf(di * (acc.y + di * xs.y));
        gv.z = f2bf(di * (acc.z + di * xs.z));
        gv.w = f2bf(di * (acc.w + di * xs.w));
        xv.x = f2bf(xs.x); xv.y = f2bf(xs.y); xv.z = f2bf(xs.z); xv.w = f2bf(xs.w);
        *(ushort4*)(gx + (long)node * 256 + c * 4) = gv;
        *(ushort4*)(gx + (long)node * 256 + 128 + c * 4) = xv;
    }
}

// ---------------------------------------------------------------------------
// out[N,128] = bf16_gemm( gx[N,256], Wab[256,128] ) + bv
// 4 waves/block, each wave: 16 rows x 128 cols via 8 accumulators of 16x16x32.
__global__ __launch_bounds__(256) void k_mm(const unsigned short* __restrict__ gx,
                                            const unsigned short* __restrict__ Wp,
                                            const float* __restrict__ bv,
                                            float* __restrict__ out) {
    const int tid = threadIdx.x;
    const int wave = tid >> 6;
    const int lane = tid & 63;
    const int quad = lane >> 4;
    const int lr = lane & 15;
    const int row0 = blockIdx.x * 64 + wave * 16;

    int ar = row0 + lr;
    if (ar >= N_NODES) ar = N_NODES - 1;  // clamp loads; stores are guarded
    const unsigned short* aptr = gx + (long)ar * 256 + quad * 8;

    f32x4 acc[8] = {};  // 8 column tiles of 16

#pragma unroll
    for (int s = 0; s < 8; ++s) {
        const short8 a = *(const short8*)(aptr + s * 32);
#pragma unroll
        for (int t = 0; t < 8; ++t) {
            const short8 b = *(const short8*)(Wp + ((long)(s * 8 + t) * 64 + lane) * 8);
            acc[t] = __builtin_amdgcn_mfma_f32_16x16x32_bf16(a, b, acc[t], 0, 0, 0);
        }
    }

#pragma unroll
    for (int t = 0; t < 8; ++t) {
        const int col = t * 16 + lr;
        const float bvv = bv[col];
#pragma unroll
        for (int r = 0; r < 4; ++r) {
            const int row = row0 + quad * 4 + r;
            if (row < N_NODES) out[(long)row * D + col] = acc[t][r] + bvv;
        }
    }
}

// ---------------------------------------------------------------------------
extern "C" void kernel_launch(void* const* d_in, const int* in_sizes, int n_in,
                              void* d_out, int out_size, void* d_ws, size_t ws_size,
                              hipStream_t stream) {
    const float* x  = (const float*)d_in[0];
    const int*   ei = (const int*)d_in[1];  // [2, E] flat: row0=src, row1=dst
    const float* Wc = (const float*)d_in[2];
    const float* bc = (const float*)d_in[3];
    const float* W0 = (const float*)d_in[4];
    const float* Wt = (const float*)d_in[5];
    float* out = (float*)d_out;

    const int* src = ei;
    const int* dst = ei + N_EDGES;

    // workspace layout:
    //   gx bf16 [N*256] | cnt [N] | cursor [N] | row_start [N] | dinv [N] |
    //   esrc [E] | Wa f32 [D*D] | Wb f32 [D*D] | bv f32 [D] | Wp bf16 [256*128]
    unsigned short* gx = (unsigned short*)d_ws;
    int*   cnt       = (int*)(gx + (size_t)N_NODES * 256);
    int*   cursor    = cnt + N_NODES;
    int*   row_start = cursor + N_NODES;
    float* dinv      = (float*)(row_start + N_NODES);
    int*   esrc      = (int*)(dinv + N_NODES);
    float* Wa        = (float*)(esrc + N_EDGES);
    float* Wb        = Wa + D * D;
    float* bv        = Wb + D * D;
    unsigned short* Wp = (unsigned short*)(bv + D);

    hipMemsetAsync(cnt, 0, 2 * (size_t)N_NODES * sizeof(int), stream);

    k_hist<<<(N_EDGES + 255) / 256, 256, 0, stream>>>(dst, cnt);
    k_scan<<<1, SCAN_T, 0, stream>>>(cnt, row_start);
    k_dinv<<<(N_NODES + 255) / 256, 256, 0, stream>>>(cnt, dinv);
    k_reorder<<<(N_EDGES + 255) / 256, 256, 0, stream>>>(src, dst, row_start, cursor, esrc);

    k_wprep<<<D, D, 0, stream>>>(Wc, W0, Wt, Wa, Wb);
    k_bprep<<<1, D, 0, stream>>>(bc, Wt, bv);
    k_wpack<<<16, 256, 0, stream>>>(Wa, Wb, Wp);

    k_gather<<<(N_NODES + 3) / 4, 256, 0, stream>>>(x, row_start, cnt, esrc, dinv, gx);

    k_mm<<<(N_NODES + 63) / 64, 256, 0, stream>>>(gx, Wp, bv, out);
}

// Round 5
// 254.709 us; speedup vs baseline: 7.1626x; 1.3339x over previous
//
#include <hip/hip_runtime.h>

#define N_NODES 50000
#define N_EDGES 800000
#define D 128
#define SBLK 256
#define NSBLK ((N_NODES + SBLK - 1) / SBLK)  // 196

typedef __attribute__((ext_vector_type(8))) short short8;
typedef __attribute__((ext_vector_type(4))) float f32x4;

// round-to-nearest-even f32 -> bf16 (as ushort)
__device__ __forceinline__ unsigned short f2bf(float f) {
    unsigned int u = __builtin_bit_cast(unsigned int, f);
    u += 0x7FFFu + ((u >> 16) & 1u);
    return (unsigned short)(u >> 16);
}

// ---------------------------------------------------------------------------
// cnt[dst[e]] += 1   (int histogram; cnt pre-zeroed by memset)
__global__ void k_hist(const int* __restrict__ dst, int* __restrict__ cnt) {
    int e = blockIdx.x * blockDim.x + threadIdx.x;
    if (e < N_EDGES) atomicAdd(&cnt[dst[e]], 1);
}

// ---------------------------------------------------------------------------
// Phase 1: per-block sums of cnt
__global__ __launch_bounds__(SBLK) void k_bsum(const int* __restrict__ cnt,
                                               int* __restrict__ bsum) {
    __shared__ int s[SBLK];
    const int t = threadIdx.x;
    const int i = blockIdx.x * SBLK + t;
    s[t] = (i < N_NODES) ? cnt[i] : 0;
    __syncthreads();
    for (int off = SBLK / 2; off > 0; off >>= 1) {
        if (t < off) s[t] += s[t + off];
        __syncthreads();
    }
    if (t == 0) bsum[blockIdx.x] = s[0];
}

// Phase 2: single-block exclusive scan of bsum[NSBLK] -> boff
__global__ __launch_bounds__(SBLK) void k_bscan(const int* __restrict__ bsum,
                                                int* __restrict__ boff) {
    __shared__ int s[SBLK];
    const int t = threadIdx.x;
    s[t] = (t < NSBLK) ? bsum[t] : 0;
    __syncthreads();
    for (int off = 1; off < SBLK; off <<= 1) {
        int v = (t >= off) ? s[t - off] : 0;
        __syncthreads();
        s[t] += v;
        __syncthreads();
    }
    if (t < NSBLK) boff[t] = (t > 0) ? s[t - 1] : 0;
}

// Phase 3: local exclusive scan + block offset -> row_start; fused dinv
__global__ __launch_bounds__(SBLK) void k_scan3(const int* __restrict__ cnt,
                                                const int* __restrict__ boff,
                                                int* __restrict__ row_start,
                                                float* __restrict__ dinv) {
    __shared__ int s[SBLK];
    const int t = threadIdx.x;
    const int i = blockIdx.x * SBLK + t;
    const int c = (i < N_NODES) ? cnt[i] : 0;
    s[t] = c;
    __syncthreads();
    for (int off = 1; off < SBLK; off <<= 1) {
        int v = (t >= off) ? s[t - off] : 0;
        __syncthreads();
        s[t] += v;
        __syncthreads();
    }
    if (i < N_NODES) {
        row_start[i] = boff[blockIdx.x] + s[t] - c;  // exclusive
        dinv[i] = rsqrtf((float)c + 1.0f);
    }
}

// esrc[row_start[dst] + cursor[dst]++] = src   (cursor pre-zeroed)
__global__ void k_reorder(const int* __restrict__ src, const int* __restrict__ dst,
                          const int* __restrict__ row_start, int* __restrict__ cursor,
                          int* __restrict__ esrc) {
    int e = blockIdx.x * blockDim.x + threadIdx.x;
    if (e >= N_EDGES) return;
    int d = dst[e];
    int pos = row_start[d] + atomicAdd(&cursor[d], 1);
    esrc[pos] = src[e];
}

// ---------------------------------------------------------------------------
// Wa = Wc + Wc@Wt,  Wb = W0 - Wt      (128 blocks x 128 threads, f32)
__global__ void k_wprep(const float* __restrict__ Wc, const float* __restrict__ W0,
                        const float* __restrict__ Wt, float* __restrict__ Wa,
                        float* __restrict__ Wb) {
    __shared__ float wr[D];
    const int i = blockIdx.x, j = threadIdx.x;
    wr[j] = Wc[i * D + j];
    __syncthreads();
    float acc = wr[j];
#pragma unroll 16
    for (int k = 0; k < D; ++k) acc += wr[k] * Wt[k * D + j];
    Wa[i * D + j] = acc;
    Wb[i * D + j] = W0[i * D + j] - Wt[i * D + j];
}

// bv = bc + bc@Wt    (1 block x 128 threads, f32)
__global__ void k_bprep(const float* __restrict__ bc, const float* __restrict__ Wt,
                        float* __restrict__ bv) {
    const int j = threadIdx.x;
    float acc = bc[j];
#pragma unroll 16
    for (int k = 0; k < D; ++k) acc += bc[k] * Wt[k * D + j];
    bv[j] = acc;
}

// Pack Wab = [Wa; Wb] (256 x 128) into bf16 B-fragment order for 16x16x32:
// Wp[((step*8 + tile)*64 + lane)*8 + j] = Wab[step*32 + (lane>>4)*8 + j][tile*16 + (lane&15)]
__global__ void k_wpack(const float* __restrict__ Wa, const float* __restrict__ Wb,
                        unsigned short* __restrict__ Wp) {
    const int id = blockIdx.x * blockDim.x + threadIdx.x;  // 0..4095
    const int lane = id & 63;
    const int tile = (id >> 6) & 7;
    const int step = id >> 9;
    const int n = tile * 16 + (lane & 15);
    const int kbase = step * 32 + (lane >> 4) * 8;
    unsigned short v[8];
#pragma unroll
    for (int j = 0; j < 8; ++j) {
        const int k = kbase + j;
        const float f = (k < D) ? Wa[k * D + n] : Wb[(k - D) * D + n];
        v[j] = f2bf(f);
    }
    *(uint4*)(Wp + (long)id * 8) = *(uint4*)v;
}

// ---------------------------------------------------------------------------
// Gather: one 64-lane wave per node (4 nodes / 256-thread block).
//   g[node] = dinv[node] * ( sum_e dinv[src_e]*x[src_e] + dinv[node]*x[node] )
// Writes bf16: gx[node][0:128] = g, gx[node][128:256] = x  (A matrix for k_mm).
__global__ __launch_bounds__(256) void k_gather(const float* __restrict__ x,
                                                const int* __restrict__ row_start,
                                                const int* __restrict__ cnt,
                                                const int* __restrict__ esrc,
                                                const float* __restrict__ dinv,
                                                unsigned short* __restrict__ gx) {
    const int node = blockIdx.x * 4 + (threadIdx.x >> 6);
    const int lane = threadIdx.x & 63;
    const int c = lane & 31;   // float4 column chunk
    const int s = lane >> 5;   // edge slot 0/1
    const int begin = row_start[node];
    const int end = begin + cnt[node];
    const float4* x4 = (const float4*)x;

    float4 acc = {0.f, 0.f, 0.f, 0.f};
    int i = begin + s;
    for (; i + 2 < end; i += 4) {  // two edges in flight per slot
        const int a0 = esrc[i];
        const int a1 = esrc[i + 2];
        const float n0 = dinv[a0];
        const float n1 = dinv[a1];
        const float4 v0 = x4[(long)a0 * 32 + c];
        const float4 v1 = x4[(long)a1 * 32 + c];
        acc.x += n0 * v0.x; acc.y += n0 * v0.y; acc.z += n0 * v0.z; acc.w += n0 * v0.w;
        acc.x += n1 * v1.x; acc.y += n1 * v1.y; acc.z += n1 * v1.z; acc.w += n1 * v1.w;
    }
    if (i < end) {
        const int a0 = esrc[i];
        const float n0 = dinv[a0];
        const float4 v0 = x4[(long)a0 * 32 + c];
        acc.x += n0 * v0.x; acc.y += n0 * v0.y; acc.z += n0 * v0.z; acc.w += n0 * v0.w;
    }

    // combine the two slots (partner lane differs only in bit 5)
    acc.x += __shfl_xor(acc.x, 32);
    acc.y += __shfl_xor(acc.y, 32);
    acc.z += __shfl_xor(acc.z, 32);
    acc.w += __shfl_xor(acc.w, 32);

    if (s == 0) {
        const float di = dinv[node];
        const float4 xs = x4[(long)node * 32 + c];
        ushort4 gv, xv;
        gv.x = f2bf(di * (acc.x + di * xs.x));
        gv.y = f2bf(di * (acc.y + di * xs.y));
        gv.z = f2bf(di * (acc.z + di * xs.z));
        gv.w = f2bf(di * (acc.w + di * xs.w));
        xv.x = f2bf(xs.x); xv.y = f2bf(xs.y); xv.z = f2bf(xs.z); xv.w = f2bf(xs.w);
        *(ushort4*)(gx + (long)node * 256 + c * 4) = gv;
        *(ushort4*)(gx + (long)node * 256 + 128 + c * 4) = xv;
    }
}

// ---------------------------------------------------------------------------
// out[N,128] = bf16_gemm( gx[N,256], Wab[256,128] ) + bv
// 4 waves/block, each wave: 16 rows x 128 cols via 8 accumulators of 16x16x32.
__global__ __launch_bounds__(256) void k_mm(const unsigned short* __restrict__ gx,
                                            const unsigned short* __restrict__ Wp,
                                            const float* __restrict__ bv,
                                            float* __restrict__ out) {
    const int tid = threadIdx.x;
    const int wave = tid >> 6;
    const int lane = tid & 63;
    const int quad = lane >> 4;
    const int lr = lane & 15;
    const int row0 = blockIdx.x * 64 + wave * 16;

    int ar = row0 + lr;
    if (ar >= N_NODES) ar = N_NODES - 1;  // clamp loads; stores are guarded
    const unsigned short* aptr = gx + (long)ar * 256 + quad * 8;

    f32x4 acc[8] = {};  // 8 column tiles of 16

#pragma unroll
    for (int s = 0; s < 8; ++s) {
        const short8 a = *(const short8*)(aptr + s * 32);
#pragma unroll
        for (int t = 0; t < 8; ++t) {
            const short8 b = *(const short8*)(Wp + ((long)(s * 8 + t) * 64 + lane) * 8);
            acc[t] = __builtin_amdgcn_mfma_f32_16x16x32_bf16(a, b, acc[t], 0, 0, 0);
        }
    }

#pragma unroll
    for (int t = 0; t < 8; ++t) {
        const int col = t * 16 + lr;
        const float bvv = bv[col];
#pragma unroll
        for (int r = 0; r < 4; ++r) {
            const int row = row0 + quad * 4 + r;
            if (row < N_NODES) out[(long)row * D + col] = acc[t][r] + bvv;
        }
    }
}

// ---------------------------------------------------------------------------
extern "C" void kernel_launch(void* const* d_in, const int* in_sizes, int n_in,
                              void* d_out, int out_size, void* d_ws, size_t ws_size,
                              hipStream_t stream) {
    const float* x  = (const float*)d_in[0];
    const int*   ei = (const int*)d_in[1];  // [2, E] flat: row0=src, row1=dst
    const float* Wc = (const float*)d_in[2];
    const float* bc = (const float*)d_in[3];
    const float* W0 = (const float*)d_in[4];
    const float* Wt = (const float*)d_in[5];
    float* out = (float*)d_out;

    const int* src = ei;
    const int* dst = ei + N_EDGES;

    // workspace layout:
    //   gx bf16 [N*256] | cnt [N] | cursor [N] | row_start [N] | dinv [N] |
    //   esrc [E] | Wa f32 [D*D] | Wb f32 [D*D] | bv f32 [D] | Wp bf16 [256*128] |
    //   bsum [NSBLK] | boff [NSBLK]
    unsigned short* gx = (unsigned short*)d_ws;
    int*   cnt       = (int*)(gx + (size_t)N_NODES * 256);
    int*   cursor    = cnt + N_NODES;
    int*   row_start = cursor + N_NODES;
    float* dinv      = (float*)(row_start + N_NODES);
    int*   esrc      = (int*)(dinv + N_NODES);
    float* Wa        = (float*)(esrc + N_EDGES);
    float* Wb        = Wa + D * D;
    float* bv        = Wb + D * D;
    unsigned short* Wp = (unsigned short*)(bv + D);
    int*   bsum      = (int*)(Wp + 256 * D);
    int*   boff      = bsum + NSBLK;

    hipMemsetAsync(cnt, 0, 2 * (size_t)N_NODES * sizeof(int), stream);

    k_hist<<<(N_EDGES + 255) / 256, 256, 0, stream>>>(dst, cnt);
    k_bsum<<<NSBLK, SBLK, 0, stream>>>(cnt, bsum);
    k_bscan<<<1, SBLK, 0, stream>>>(bsum, boff);
    k_scan3<<<NSBLK, SBLK, 0, stream>>>(cnt, boff, row_start, dinv);
    k_reorder<<<(N_EDGES + 255) / 256, 256, 0, stream>>>(src, dst, row_start, cursor, esrc);

    k_wprep<<<D, D, 0, stream>>>(Wc, W0, Wt, Wa, Wb);
    k_bprep<<<1, D, 0, stream>>>(bc, Wt, bv);
    k_wpack<<<16, 256, 0, stream>>>(Wa, Wb, Wp);

    k_gather<<<(N_NODES + 3) / 4, 256, 0, stream>>>(x, row_start, cnt, esrc, dinv, gx);

    k_mm<<<(N_NODES + 63) / 64, 256, 0, stream>>>(gx, Wp, bv, out);
}

// Round 6
// 251.385 us; speedup vs baseline: 7.2573x; 1.0132x over previous
//
#include <hip/hip_runtime.h>

#define N_NODES 50000
#define N_EDGES 800000
#define D 128
#define SBLK 256
#define NSBLK ((N_NODES + SBLK - 1) / SBLK)  // 196

typedef __attribute__((ext_vector_type(8))) short short8;
typedef __attribute__((ext_vector_type(4))) float f32x4;

// round-to-nearest-even f32 -> bf16 (as ushort)
__device__ __forceinline__ unsigned short f2bf(float f) {
    unsigned int u = __builtin_bit_cast(unsigned int, f);
    u += 0x7FFFu + ((u >> 16) & 1u);
    return (unsigned short)(u >> 16);
}
__device__ __forceinline__ float bf2f(unsigned short h) {
    unsigned int u = ((unsigned int)h) << 16;
    return __builtin_bit_cast(float, u);
}

// ---------------------------------------------------------------------------
// cnt[dst[e]] += 1   (int histogram; cnt pre-zeroed by memset)
__global__ void k_hist(const int* __restrict__ dst, int* __restrict__ cnt) {
    int e = blockIdx.x * blockDim.x + threadIdx.x;
    if (e < N_EDGES) atomicAdd(&cnt[dst[e]], 1);
}

// ---------------------------------------------------------------------------
// Phase 1: per-block sums of cnt
__global__ __launch_bounds__(SBLK) void k_bsum(const int* __restrict__ cnt,
                                               int* __restrict__ bsum) {
    __shared__ int s[SBLK];
    const int t = threadIdx.x;
    const int i = blockIdx.x * SBLK + t;
    s[t] = (i < N_NODES) ? cnt[i] : 0;
    __syncthreads();
    for (int off = SBLK / 2; off > 0; off >>= 1) {
        if (t < off) s[t] += s[t + off];
        __syncthreads();
    }
    if (t == 0) bsum[blockIdx.x] = s[0];
}

// Phase 2: single-block exclusive scan of bsum[NSBLK] -> boff
__global__ __launch_bounds__(SBLK) void k_bscan(const int* __restrict__ bsum,
                                                int* __restrict__ boff) {
    __shared__ int s[SBLK];
    const int t = threadIdx.x;
    s[t] = (t < NSBLK) ? bsum[t] : 0;
    __syncthreads();
    for (int off = 1; off < SBLK; off <<= 1) {
        int v = (t >= off) ? s[t - off] : 0;
        __syncthreads();
        s[t] += v;
        __syncthreads();
    }
    if (t < NSBLK) boff[t] = (t > 0) ? s[t - 1] : 0;
}

// Phase 3: local exclusive scan + block offset -> row_start (+ cursor copy); fused dinv
__global__ __launch_bounds__(SBLK) void k_scan3(const int* __restrict__ cnt,
                                                const int* __restrict__ boff,
                                                int* __restrict__ row_start,
                                                int* __restrict__ cursor,
                                                float* __restrict__ dinv) {
    __shared__ int s[SBLK];
    const int t = threadIdx.x;
    const int i = blockIdx.x * SBLK + t;
    const int c = (i < N_NODES) ? cnt[i] : 0;
    s[t] = c;
    __syncthreads();
    for (int off = 1; off < SBLK; off <<= 1) {
        int v = (t >= off) ? s[t - off] : 0;
        __syncthreads();
        s[t] += v;
        __syncthreads();
    }
    if (i < N_NODES) {
        const int rs = boff[blockIdx.x] + s[t] - c;  // exclusive
        row_start[i] = rs;
        cursor[i] = rs;
        dinv[i] = rsqrtf((float)c + 1.0f);
    }
}

// esrc[cursor[dst]++] = src   (cursor pre-initialized to row_start)
__global__ void k_reorder(const int* __restrict__ src, const int* __restrict__ dst,
                          int* __restrict__ cursor, int* __restrict__ esrc) {
    int e = blockIdx.x * blockDim.x + threadIdx.x;
    if (e >= N_EDGES) return;
    int pos = atomicAdd(&cursor[dst[e]], 1);
    esrc[pos] = src[e];
}

// ---------------------------------------------------------------------------
// Fused weight prep + pack. Wab = [Wc + Wc@Wt ; W0 - Wt] (256 x 128) packed in
// bf16 B-fragment order for 16x16x32:
//   Wp[((step*8+tile)*64+lane)*8 + j] = Wab[step*32 + (lane>>4)*8 + j][tile*16 + (lane&15)]
// Blocks 0..15: pack (computing Wab on the fly, Wt staged in LDS).
// Block 16: bv = bc + bc@Wt.
__global__ __launch_bounds__(256) void k_wpack(const float* __restrict__ Wc,
                                               const float* __restrict__ W0,
                                               const float* __restrict__ Wt,
                                               const float* __restrict__ bc,
                                               unsigned short* __restrict__ Wp,
                                               float* __restrict__ bv) {
    __shared__ float sWt[D * D];
    const int t = threadIdx.x;
    for (int i = t * 4; i < D * D; i += 256 * 4)
        *(float4*)(sWt + i) = *(const float4*)(Wt + i);
    __syncthreads();

    if (blockIdx.x == 16) {
        if (t < D) {
            float acc = bc[t];
#pragma unroll 16
            for (int k = 0; k < D; ++k) acc += bc[k] * sWt[k * D + t];
            bv[t] = acc;
        }
        return;
    }
    const int id = blockIdx.x * 256 + t;  // 0..4095
    const int lane = id & 63;
    const int tile = (id >> 6) & 7;
    const int step = id >> 9;
    const int n = tile * 16 + (lane & 15);
    const int kbase = step * 32 + (lane >> 4) * 8;
    unsigned short v[8];
#pragma unroll
    for (int j = 0; j < 8; ++j) {
        const int k = kbase + j;
        float f;
        if (k < D) {
            f = Wc[k * D + n];
#pragma unroll 16
            for (int m = 0; m < D; ++m) f += Wc[k * D + m] * sWt[m * D + n];
        } else {
            f = W0[(k - D) * D + n] - sWt[(k - D) * D + n];
        }
        v[j] = f2bf(f);
    }
    *(uint4*)(Wp + (long)id * 8) = *(uint4*)v;
}

// ---------------------------------------------------------------------------
// xd[n] = bf16(dinv[n] * x[n])  and  gx[n][128:256] = bf16(x[n])
// one thread per 8-element chunk: 50000*16 threads
__global__ __launch_bounds__(256) void k_xcast(const float* __restrict__ x,
                                               const float* __restrict__ dinv,
                                               unsigned short* __restrict__ xd,
                                               unsigned short* __restrict__ gx) {
    const int gid = blockIdx.x * 256 + threadIdx.x;  // 0 .. N*16-1
    const int node = gid >> 4;
    const int c = gid & 15;
    const float di = dinv[node];
    const float4 a = ((const float4*)x)[(long)node * 32 + c * 2];
    const float4 b = ((const float4*)x)[(long)node * 32 + c * 2 + 1];
    const float f[8] = {a.x, a.y, a.z, a.w, b.x, b.y, b.z, b.w};
    unsigned short vd[8], vb[8];
#pragma unroll
    for (int j = 0; j < 8; ++j) {
        vd[j] = f2bf(di * f[j]);
        vb[j] = f2bf(f[j]);
    }
    *(uint4*)(xd + (long)node * 128 + c * 8) = *(uint4*)vd;
    *(uint4*)(gx + (long)node * 256 + 128 + c * 8) = *(uint4*)vb;
}

// ---------------------------------------------------------------------------
// Gather (bf16 rows): one 64-lane wave per node (4 nodes / block).
//   g[n] = dinv[n] * ( sum_e xd[src_e] + xd[n] )      (xd is pre-scaled by dinv)
// Lane layout: c = lane&15 -> 8-elem chunk (16 B), s = lane>>4 -> edge slot 0..3.
// Writes bf16 g into gx[n][0:128].
__global__ __launch_bounds__(256) void k_gather(const unsigned short* __restrict__ xd,
                                                const int* __restrict__ row_start,
                                                const int* __restrict__ cnt,
                                                const int* __restrict__ esrc,
                                                const float* __restrict__ dinv,
                                                unsigned short* __restrict__ gx) {
    const int node = blockIdx.x * 4 + (threadIdx.x >> 6);
    const int lane = threadIdx.x & 63;
    const int c = lane & 15;
    const int s = lane >> 4;
    const int begin = row_start[node];
    const int end = begin + cnt[node];

    float acc[8] = {};
    int i = begin + s;
    for (; i + 4 < end; i += 8) {  // two edges in flight per slot
        const int a0 = esrc[i];
        const int a1 = esrc[i + 4];
        const short8 v0 = *(const short8*)(xd + (long)a0 * 128 + c * 8);
        const short8 v1 = *(const short8*)(xd + (long)a1 * 128 + c * 8);
#pragma unroll
        for (int j = 0; j < 8; ++j)
            acc[j] += bf2f((unsigned short)v0[j]) + bf2f((unsigned short)v1[j]);
    }
    if (i < end) {
        const int a0 = esrc[i];
        const short8 v0 = *(const short8*)(xd + (long)a0 * 128 + c * 8);
#pragma unroll
        for (int j = 0; j < 8; ++j) acc[j] += bf2f((unsigned short)v0[j]);
    }

    // combine 4 slots (partner lanes differ in bits 4,5)
#pragma unroll
    for (int j = 0; j < 8; ++j) {
        acc[j] += __shfl_xor(acc[j], 16);
        acc[j] += __shfl_xor(acc[j], 32);
    }

    if (s == 0) {
        const float di = dinv[node];
        const short8 xs = *(const short8*)(xd + (long)node * 128 + c * 8);
        unsigned short o[8];
#pragma unroll
        for (int j = 0; j < 8; ++j)
            o[j] = f2bf(di * (acc[j] + bf2f((unsigned short)xs[j])));
        *(uint4*)(gx + (long)node * 256 + c * 8) = *(uint4*)o;
    }
}

// ---------------------------------------------------------------------------
// out[N,128] = bf16_gemm( gx[N,256], Wab[256,128] ) + bv
// 4 waves/block, each wave: 16 rows x 128 cols via 8 accumulators of 16x16x32.
__global__ __launch_bounds__(256) void k_mm(const unsigned short* __restrict__ gx,
                                            const unsigned short* __restrict__ Wp,
                                            const float* __restrict__ bv,
                                            float* __restrict__ out) {
    const int tid = threadIdx.x;
    const int wave = tid >> 6;
    const int lane = tid & 63;
    const int quad = lane >> 4;
    const int lr = lane & 15;
    const int row0 = blockIdx.x * 64 + wave * 16;

    int ar = row0 + lr;
    if (ar >= N_NODES) ar = N_NODES - 1;  // clamp loads; stores are guarded
    const unsigned short* aptr = gx + (long)ar * 256 + quad * 8;

    f32x4 acc[8] = {};  // 8 column tiles of 16

#pragma unroll
    for (int s = 0; s < 8; ++s) {
        const short8 a = *(const short8*)(aptr + s * 32);
#pragma unroll
        for (int t = 0; t < 8; ++t) {
            const short8 b = *(const short8*)(Wp + ((long)(s * 8 + t) * 64 + lane) * 8);
            acc[t] = __builtin_amdgcn_mfma_f32_16x16x32_bf16(a, b, acc[t], 0, 0, 0);
        }
    }

#pragma unroll
    for (int t = 0; t < 8; ++t) {
        const int col = t * 16 + lr;
        const float bvv = bv[col];
#pragma unroll
        for (int r = 0; r < 4; ++r) {
            const int row = row0 + quad * 4 + r;
            if (row < N_NODES) out[(long)row * D + col] = acc[t][r] + bvv;
        }
    }
}

// ---------------------------------------------------------------------------
extern "C" void kernel_launch(void* const* d_in, const int* in_sizes, int n_in,
                              void* d_out, int out_size, void* d_ws, size_t ws_size,
                              hipStream_t stream) {
    const float* x  = (const float*)d_in[0];
    const int*   ei = (const int*)d_in[1];  // [2, E] flat: row0=src, row1=dst
    const float* Wc = (const float*)d_in[2];
    const float* bc = (const float*)d_in[3];
    const float* W0 = (const float*)d_in[4];
    const float* Wt = (const float*)d_in[5];
    float* out = (float*)d_out;

    const int* src = ei;
    const int* dst = ei + N_EDGES;

    // workspace layout:
    //   gx bf16 [N*256] | xd bf16 [N*128] | cnt [N] | cursor [N] | row_start [N] |
    //   dinv [N] | esrc [E] | bv f32 [D] | Wp bf16 [256*128] | bsum | boff
    unsigned short* gx = (unsigned short*)d_ws;
    unsigned short* xd = gx + (size_t)N_NODES * 256;
    int*   cnt       = (int*)(xd + (size_t)N_NODES * 128);
    int*   cursor    = cnt + N_NODES;
    int*   row_start = cursor + N_NODES;
    float* dinv      = (float*)(row_start + N_NODES);
    int*   esrc      = (int*)(dinv + N_NODES);
    float* bv        = (float*)(esrc + N_EDGES);
    unsigned short* Wp = (unsigned short*)(bv + D);
    int*   bsum      = (int*)(Wp + 256 * D);
    int*   boff      = bsum + NSBLK;

    hipMemsetAsync(cnt, 0, (size_t)N_NODES * sizeof(int), stream);

    k_hist<<<(N_EDGES + 255) / 256, 256, 0, stream>>>(dst, cnt);
    k_bsum<<<NSBLK, SBLK, 0, stream>>>(cnt, bsum);
    k_bscan<<<1, SBLK, 0, stream>>>(bsum, boff);
    k_scan3<<<NSBLK, SBLK, 0, stream>>>(cnt, boff, row_start, cursor, dinv);
    k_reorder<<<(N_EDGES + 255) / 256, 256, 0, stream>>>(src, dst, cursor, esrc);

    k_wpack<<<17, 256, 0, stream>>>(Wc, W0, Wt, bc, Wp, bv);

    k_xcast<<<(N_NODES * 16) / 256, 256, 0, stream>>>(x, dinv, xd, gx);

    k_gather<<<N_NODES / 4, 256, 0, stream>>>(xd, row_start, cnt, esrc, dinv, gx);

    k_mm<<<(N_NODES + 63) / 64, 256, 0, stream>>>(gx, Wp, bv, out);
}

// Round 7
// 197.792 us; speedup vs baseline: 9.2237x; 1.2710x over previous
//
#include <hip/hip_runtime.h>

#define N_NODES 50000
#define N_EDGES 800000
#define D 128
#define NB 196                 // buckets: bucket = dst >> 8, 256 nodes each
#define P1_BLOCKS 128
#define EPB ((N_EDGES + P1_BLOCKS - 1) / P1_BLOCKS)  // 6250 edges/block
#define CAP 64                 // LDS staging slots per bucket in part1

typedef __attribute__((ext_vector_type(8))) short short8;
typedef __attribute__((ext_vector_type(4))) float f32x4;

// round-to-nearest-even f32 -> bf16 (as ushort)
__device__ __forceinline__ unsigned short f2bf(float f) {
    unsigned int u = __builtin_bit_cast(unsigned int, f);
    u += 0x7FFFu + ((u >> 16) & 1u);
    return (unsigned short)(u >> 16);
}
__device__ __forceinline__ float bf2f(unsigned short h) {
    unsigned int u = ((unsigned int)h) << 16;
    return __builtin_bit_cast(float, u);
}

// ---------------------------------------------------------------------------
// Per-bucket edge counts (LDS hist per block, one global atomic/bucket/block)
__global__ __launch_bounds__(256) void k_bcnt(const int* __restrict__ dst,
                                              int* __restrict__ bcnt) {
    __shared__ int h[NB];
    const int t = threadIdx.x;
    for (int i = t; i < NB; i += 256) h[i] = 0;
    __syncthreads();
    const long e0 = (long)blockIdx.x * EPB;
    const long e1 = (e0 + EPB < N_EDGES) ? e0 + EPB : N_EDGES;
    for (long e = e0 + t; e < e1; e += 256) atomicAdd(&h[dst[e] >> 8], 1);
    __syncthreads();
    for (int i = t; i < NB; i += 256)
        if (h[i]) atomicAdd(&bcnt[i], h[i]);
}

// Exclusive scan of bcnt[NB] -> bucket_base; gcur initialized to base
__global__ __launch_bounds__(256) void k_bscan2(const int* __restrict__ bcnt,
                                                int* __restrict__ bucket_base,
                                                int* __restrict__ gcur) {
    __shared__ int s[256];
    const int t = threadIdx.x;
    const int v = (t < NB) ? bcnt[t] : 0;
    s[t] = v;
    __syncthreads();
    for (int off = 1; off < 256; off <<= 1) {
        int u = (t >= off) ? s[t - off] : 0;
        __syncthreads();
        s[t] += u;
        __syncthreads();
    }
    if (t < NB) {
        const int base = s[t] - v;
        bucket_base[t] = base;
        gcur[t] = base;
    }
}

// Partition edges into buckets with LDS write-combining.
// pbuf code: (local_dst << 16) | src   (src < 65536, local_dst < 256)
__global__ __launch_bounds__(256) void k_part1(const int* __restrict__ src,
                                               const int* __restrict__ dst,
                                               int* __restrict__ gcur,
                                               unsigned int* __restrict__ pbuf) {
    __shared__ unsigned int stage[NB][CAP + 1];  // +1 pad: drain reads conflict-free
    __shared__ int scnt[NB];
    const int t = threadIdx.x;
    for (int i = t; i < NB; i += 256) scnt[i] = 0;
    __syncthreads();

    const long e0 = (long)blockIdx.x * EPB;
    const long e1 = (e0 + EPB < N_EDGES) ? e0 + EPB : N_EDGES;
    for (long e = e0 + t; e < e1; e += 256) {
        const int s = src[e];
        const int d = dst[e];
        const int b = d >> 8;
        const unsigned int p = ((unsigned int)(d & 255) << 16) | (unsigned int)s;
        const int slot = atomicAdd(&scnt[b], 1);
        if (slot < CAP) {
            stage[b][slot] = p;
        } else {  // spill (statistically ~never; correctness for any distribution)
            const int pos = atomicAdd(&gcur[b], 1);
            pbuf[pos] = p;
        }
    }
    __syncthreads();
    // cooperative drain: thread t drains bucket t in one contiguous burst
    if (t < NB) {
        const int n = (scnt[t] < CAP) ? scnt[t] : CAP;
        if (n > 0) {
            const int pos = atomicAdd(&gcur[t], n);
            for (int i = 0; i < n; ++i) pbuf[pos + i] = stage[t][i];
        }
    }
}

// Per-bucket local CSR build: hist + scan in LDS, scatter into L2-local window.
// Also produces row_start / cnt / dinv (replaces the old global hist+scan).
__global__ __launch_bounds__(256) void k_part2(const unsigned int* __restrict__ pbuf,
                                               const int* __restrict__ bucket_base,
                                               const int* __restrict__ bcnt,
                                               int* __restrict__ row_start,
                                               int* __restrict__ cnt,
                                               float* __restrict__ dinv,
                                               int* __restrict__ esrc) {
    __shared__ int lcnt[256];
    __shared__ int lcur[256];
    __shared__ int stmp[256];
    const int b = blockIdx.x;
    const int t = threadIdx.x;
    const int base = bucket_base[b];
    const int n = bcnt[b];

    lcnt[t] = 0;
    __syncthreads();
    for (int i = t; i < n; i += 256) atomicAdd(&lcnt[pbuf[base + i] >> 16], 1);
    __syncthreads();

    const int c = lcnt[t];
    stmp[t] = c;
    __syncthreads();
    for (int off = 1; off < 256; off <<= 1) {
        int u = (t >= off) ? stmp[t - off] : 0;
        __syncthreads();
        stmp[t] += u;
        __syncthreads();
    }
    const int ls = base + stmp[t] - c;  // exclusive
    lcur[t] = ls;
    const int node = b * 256 + t;
    if (node < N_NODES) {
        row_start[node] = ls;
        cnt[node] = c;
        dinv[node] = rsqrtf((float)c + 1.0f);
    }
    __syncthreads();

    for (int i = t; i < n; i += 256) {
        const unsigned int p = pbuf[base + i];
        const int pos = atomicAdd(&lcur[p >> 16], 1);
        esrc[pos] = (int)(p & 0xFFFFu);
    }
}

// ---------------------------------------------------------------------------
// Fused weight prep + pack. Wab = [Wc + Wc@Wt ; W0 - Wt] (256 x 128) packed in
// bf16 B-fragment order for 16x16x32. Blocks 0..15: pack. Block 16: bv.
__global__ __launch_bounds__(256) void k_wpack(const float* __restrict__ Wc,
                                               const float* __restrict__ W0,
                                               const float* __restrict__ Wt,
                                               const float* __restrict__ bc,
                                               unsigned short* __restrict__ Wp,
                                               float* __restrict__ bv) {
    __shared__ float sWt[D * D];
    const int t = threadIdx.x;
    for (int i = t * 4; i < D * D; i += 256 * 4)
        *(float4*)(sWt + i) = *(const float4*)(Wt + i);
    __syncthreads();

    if (blockIdx.x == 16) {
        if (t < D) {
            float acc = bc[t];
#pragma unroll 16
            for (int k = 0; k < D; ++k) acc += bc[k] * sWt[k * D + t];
            bv[t] = acc;
        }
        return;
    }
    const int id = blockIdx.x * 256 + t;  // 0..4095
    const int lane = id & 63;
    const int tile = (id >> 6) & 7;
    const int step = id >> 9;
    const int n = tile * 16 + (lane & 15);
    const int kbase = step * 32 + (lane >> 4) * 8;
    unsigned short v[8];
#pragma unroll
    for (int j = 0; j < 8; ++j) {
        const int k = kbase + j;
        float f;
        if (k < D) {
            f = Wc[k * D + n];
#pragma unroll 16
            for (int m = 0; m < D; ++m) f += Wc[k * D + m] * sWt[m * D + n];
        } else {
            f = W0[(k - D) * D + n] - sWt[(k - D) * D + n];
        }
        v[j] = f2bf(f);
    }
    *(uint4*)(Wp + (long)id * 8) = *(uint4*)v;
}

// ---------------------------------------------------------------------------
// xd[n] = bf16(dinv[n] * x[n])  and  gx[n][128:256] = bf16(x[n])
__global__ __launch_bounds__(256) void k_xcast(const float* __restrict__ x,
                                               const float* __restrict__ dinv,
                                               unsigned short* __restrict__ xd,
                                               unsigned short* __restrict__ gx) {
    const int gid = blockIdx.x * 256 + threadIdx.x;  // 0 .. N*16-1
    const int node = gid >> 4;
    const int c = gid & 15;
    const float di = dinv[node];
    const float4 a = ((const float4*)x)[(long)node * 32 + c * 2];
    const float4 b = ((const float4*)x)[(long)node * 32 + c * 2 + 1];
    const float f[8] = {a.x, a.y, a.z, a.w, b.x, b.y, b.z, b.w};
    unsigned short vd[8], vb[8];
#pragma unroll
    for (int j = 0; j < 8; ++j) {
        vd[j] = f2bf(di * f[j]);
        vb[j] = f2bf(f[j]);
    }
    *(uint4*)(xd + (long)node * 128 + c * 8) = *(uint4*)vd;
    *(uint4*)(gx + (long)node * 256 + 128 + c * 8) = *(uint4*)vb;
}

// ---------------------------------------------------------------------------
// Gather (bf16 rows): one 64-lane wave per node (4 nodes / block).
//   g[n] = dinv[n] * ( sum_e xd[src_e] + xd[n] )      (xd pre-scaled by dinv)
__global__ __launch_bounds__(256) void k_gather(const unsigned short* __restrict__ xd,
                                                const int* __restrict__ row_start,
                                                const int* __restrict__ cnt,
                                                const int* __restrict__ esrc,
                                                const float* __restrict__ dinv,
                                                unsigned short* __restrict__ gx) {
    const int node = blockIdx.x * 4 + (threadIdx.x >> 6);
    const int lane = threadIdx.x & 63;
    const int c = lane & 15;
    const int s = lane >> 4;
    const int begin = row_start[node];
    const int end = begin + cnt[node];

    float acc[8] = {};
    int i = begin + s;
    for (; i + 4 < end; i += 8) {  // two edges in flight per slot
        const int a0 = esrc[i];
        const int a1 = esrc[i + 4];
        const short8 v0 = *(const short8*)(xd + (long)a0 * 128 + c * 8);
        const short8 v1 = *(const short8*)(xd + (long)a1 * 128 + c * 8);
#pragma unroll
        for (int j = 0; j < 8; ++j)
            acc[j] += bf2f((unsigned short)v0[j]) + bf2f((unsigned short)v1[j]);
    }
    if (i < end) {
        const int a0 = esrc[i];
        const short8 v0 = *(const short8*)(xd + (long)a0 * 128 + c * 8);
#pragma unroll
        for (int j = 0; j < 8; ++j) acc[j] += bf2f((unsigned short)v0[j]);
    }

#pragma unroll
    for (int j = 0; j < 8; ++j) {
        acc[j] += __shfl_xor(acc[j], 16);
        acc[j] += __shfl_xor(acc[j], 32);
    }

    if (s == 0) {
        const float di = dinv[node];
        const short8 xs = *(const short8*)(xd + (long)node * 128 + c * 8);
        unsigned short o[8];
#pragma unroll
        for (int j = 0; j < 8; ++j)
            o[j] = f2bf(di * (acc[j] + bf2f((unsigned short)xs[j])));
        *(uint4*)(gx + (long)node * 256 + c * 8) = *(uint4*)o;
    }
}

// ---------------------------------------------------------------------------
// out[N,128] = bf16_gemm( gx[N,256], Wab[256,128] ) + bv
__global__ __launch_bounds__(256) void k_mm(const unsigned short* __restrict__ gx,
                                            const unsigned short* __restrict__ Wp,
                                            const float* __restrict__ bv,
                                            float* __restrict__ out) {
    const int tid = threadIdx.x;
    const int wave = tid >> 6;
    const int lane = tid & 63;
    const int quad = lane >> 4;
    const int lr = lane & 15;
    const int row0 = blockIdx.x * 64 + wave * 16;

    int ar = row0 + lr;
    if (ar >= N_NODES) ar = N_NODES - 1;  // clamp loads; stores are guarded
    const unsigned short* aptr = gx + (long)ar * 256 + quad * 8;

    f32x4 acc[8] = {};

#pragma unroll
    for (int s = 0; s < 8; ++s) {
        const short8 a = *(const short8*)(aptr + s * 32);
#pragma unroll
        for (int t = 0; t < 8; ++t) {
            const short8 b = *(const short8*)(Wp + ((long)(s * 8 + t) * 64 + lane) * 8);
            acc[t] = __builtin_amdgcn_mfma_f32_16x16x32_bf16(a, b, acc[t], 0, 0, 0);
        }
    }

#pragma unroll
    for (int t = 0; t < 8; ++t) {
        const int col = t * 16 + lr;
        const float bvv = bv[col];
#pragma unroll
        for (int r = 0; r < 4; ++r) {
            const int row = row0 + quad * 4 + r;
            if (row < N_NODES) out[(long)row * D + col] = acc[t][r] + bvv;
        }
    }
}

// ---------------------------------------------------------------------------
extern "C" void kernel_launch(void* const* d_in, const int* in_sizes, int n_in,
                              void* d_out, int out_size, void* d_ws, size_t ws_size,
                              hipStream_t stream) {
    const float* x  = (const float*)d_in[0];
    const int*   ei = (const int*)d_in[1];  // [2, E] flat: row0=src, row1=dst
    const float* Wc = (const float*)d_in[2];
    const float* bc = (const float*)d_in[3];
    const float* W0 = (const float*)d_in[4];
    const float* Wt = (const float*)d_in[5];
    float* out = (float*)d_out;

    const int* src = ei;
    const int* dst = ei + N_EDGES;

    // workspace layout:
    //   gx bf16 [N*256] | xd bf16 [N*128] | cnt [N] | row_start [N] | dinv [N] |
    //   esrc [E] | pbuf [E] | bv f32 [D] | Wp bf16 [256*128] |
    //   bcnt [NB] | bucket_base [NB] | gcur [NB]
    unsigned short* gx = (unsigned short*)d_ws;
    unsigned short* xd = gx + (size_t)N_NODES * 256;
    int*   cnt        = (int*)(xd + (size_t)N_NODES * 128);
    int*   row_start  = cnt + N_NODES;
    float* dinv       = (float*)(row_start + N_NODES);
    int*   esrc       = (int*)(dinv + N_NODES);
    unsigned int* pbuf = (unsigned int*)(esrc + N_EDGES);
    float* bv         = (float*)(pbuf + N_EDGES);
    unsigned short* Wp = (unsigned short*)(bv + D);
    int*   bcnt       = (int*)(Wp + 256 * D);
    int*   bucket_base = bcnt + NB;
    int*   gcur       = bucket_base + NB;

    hipMemsetAsync(bcnt, 0, NB * sizeof(int), stream);

    k_bcnt<<<P1_BLOCKS, 256, 0, stream>>>(dst, bcnt);
    k_bscan2<<<1, 256, 0, stream>>>(bcnt, bucket_base, gcur);
    k_part1<<<P1_BLOCKS, 256, 0, stream>>>(src, dst, gcur, pbuf);
    k_part2<<<NB, 256, 0, stream>>>(pbuf, bucket_base, bcnt, row_start, cnt, dinv, esrc);

    k_wpack<<<17, 256, 0, stream>>>(Wc, W0, Wt, bc, Wp, bv);

    k_xcast<<<(N_NODES * 16) / 256, 256, 0, stream>>>(x, dinv, xd, gx);

    k_gather<<<N_NODES / 4, 256, 0, stream>>>(xd, row_start, cnt, esrc, dinv, gx);

    k_mm<<<(N_NODES + 63) / 64, 256, 0, stream>>>(gx, Wp, bv, out);
}

// Round 8
// 188.453 us; speedup vs baseline: 9.6808x; 1.0496x over previous
//
#include <hip/hip_runtime.h>

#define N_NODES 50000
#define N_EDGES 800000
#define D 128
#define NB 196                 // buckets: bucket = dst >> 8, 256 nodes each
#define CAPB 8192              // fixed slots per bucket (mean 4082, ~64 sigma)
#define P1_BLOCKS 128
#define EPB ((N_EDGES + P1_BLOCKS - 1) / P1_BLOCKS)  // 6250 edges/block
#define CAP 64                 // LDS staging slots per bucket in part1
#define GROWS 136              // LDS g-row stride in shorts (272 B: 16B-aligned, 2-way banks)

typedef __attribute__((ext_vector_type(8))) short short8;
typedef __attribute__((ext_vector_type(4))) float f32x4;

// round-to-nearest-even f32 -> bf16 (as ushort)
__device__ __forceinline__ unsigned short f2bf(float f) {
    unsigned int u = __builtin_bit_cast(unsigned int, f);
    u += 0x7FFFu + ((u >> 16) & 1u);
    return (unsigned short)(u >> 16);
}
__device__ __forceinline__ float bf2f(unsigned short h) {
    unsigned int u = ((unsigned int)h) << 16;
    return __builtin_bit_cast(float, u);
}

// ---------------------------------------------------------------------------
// gcur[b] = b * CAPB   (fixed bucket bases; replaces hist+scan+memset)
__global__ void k_init(int* __restrict__ gcur) {
    const int t = threadIdx.x;
    if (t < NB) gcur[t] = t * CAPB;
}

// Partition edges into fixed-base buckets with LDS write-combining.
// pbuf code: (local_dst << 16) | src   (src < 65536, local_dst < 256)
__global__ __launch_bounds__(256) void k_part1(const int* __restrict__ src,
                                               const int* __restrict__ dst,
                                               int* __restrict__ gcur,
                                               unsigned int* __restrict__ pbuf) {
    __shared__ unsigned int stage[NB][CAP + 1];  // +1 pad: drain reads conflict-free
    __shared__ int scnt[NB];
    const int t = threadIdx.x;
    for (int i = t; i < NB; i += 256) scnt[i] = 0;
    __syncthreads();

    const long e0 = (long)blockIdx.x * EPB;
    const long e1 = (e0 + EPB < N_EDGES) ? e0 + EPB : N_EDGES;
    for (long e = e0 + t; e < e1; e += 256) {
        const int s = src[e];
        const int d = dst[e];
        const int b = d >> 8;
        const unsigned int p = ((unsigned int)(d & 255) << 16) | (unsigned int)s;
        const int slot = atomicAdd(&scnt[b], 1);
        if (slot < CAP) {
            stage[b][slot] = p;
        } else {  // spill (statistically ~never; correctness for any distribution)
            const int pos = atomicAdd(&gcur[b], 1);
            pbuf[pos] = p;
        }
    }
    __syncthreads();
    // cooperative drain: thread t drains bucket t in one contiguous burst
    if (t < NB) {
        const int n = (scnt[t] < CAP) ? scnt[t] : CAP;
        if (n > 0) {
            const int pos = atomicAdd(&gcur[t], n);
            for (int i = 0; i < n; ++i) pbuf[pos + i] = stage[t][i];
        }
    }
}

// Per-bucket local CSR build: hist + scan in LDS, scatter into L2-local window.
// Produces row_start / cnt / dinv.
__global__ __launch_bounds__(256) void k_part2(const unsigned int* __restrict__ pbuf,
                                               const int* __restrict__ gcur,
                                               int* __restrict__ row_start,
                                               int* __restrict__ cnt,
                                               float* __restrict__ dinv,
                                               int* __restrict__ esrc) {
    __shared__ int lcnt[256];
    __shared__ int lcur[256];
    __shared__ int stmp[256];
    const int b = blockIdx.x;
    const int t = threadIdx.x;
    const int base = b * CAPB;
    const int n = gcur[b] - base;

    lcnt[t] = 0;
    __syncthreads();
    for (int i = t; i < n; i += 256) atomicAdd(&lcnt[pbuf[base + i] >> 16], 1);
    __syncthreads();

    const int c = lcnt[t];
    stmp[t] = c;
    __syncthreads();
    for (int off = 1; off < 256; off <<= 1) {
        int u = (t >= off) ? stmp[t - off] : 0;
        __syncthreads();
        stmp[t] += u;
        __syncthreads();
    }
    const int ls = base + stmp[t] - c;  // exclusive, within bucket window
    lcur[t] = ls;
    const int node = b * 256 + t;
    if (node < N_NODES) {
        row_start[node] = ls;
        cnt[node] = c;
        dinv[node] = rsqrtf((float)c + 1.0f);
    }
    __syncthreads();

    for (int i = t; i < n; i += 256) {
        const unsigned int p = pbuf[base + i];
        const int pos = atomicAdd(&lcur[p >> 16], 1);
        esrc[pos] = (int)(p & 0xFFFFu);
    }
}

// ---------------------------------------------------------------------------
// Fused weight-pack + x-cast.
// Blocks 0..15: pack Wab = [Wc + Wc@Wt ; W0 - Wt] (256x128) into bf16 B-fragment
// order for 16x16x32. Block 16: bv = bc + bc@Wt.
// Blocks 17..: xd[n] = bf16(dinv[n]*x[n]), xb[n] = bf16(x[n]).
__global__ __launch_bounds__(256) void k_wx(const float* __restrict__ Wc,
                                            const float* __restrict__ W0,
                                            const float* __restrict__ Wt,
                                            const float* __restrict__ bc,
                                            const float* __restrict__ x,
                                            const float* __restrict__ dinv,
                                            unsigned short* __restrict__ Wp,
                                            float* __restrict__ bv,
                                            unsigned short* __restrict__ xd,
                                            unsigned short* __restrict__ xb) {
    __shared__ float sWt[D * D];
    const int t = threadIdx.x;

    if (blockIdx.x < 17) {
        for (int i = t * 4; i < D * D; i += 256 * 4)
            *(float4*)(sWt + i) = *(const float4*)(Wt + i);
        __syncthreads();

        if (blockIdx.x == 16) {
            if (t < D) {
                float acc = bc[t];
#pragma unroll 16
                for (int k = 0; k < D; ++k) acc += bc[k] * sWt[k * D + t];
                bv[t] = acc;
            }
            return;
        }
        const int id = blockIdx.x * 256 + t;  // 0..4095
        const int lane = id & 63;
        const int tile = (id >> 6) & 7;
        const int step = id >> 9;
        const int n = tile * 16 + (lane & 15);
        const int kbase = step * 32 + (lane >> 4) * 8;
        unsigned short v[8];
#pragma unroll
        for (int j = 0; j < 8; ++j) {
            const int k = kbase + j;
            float f;
            if (k < D) {
                f = Wc[k * D + n];
#pragma unroll 16
                for (int m = 0; m < D; ++m) f += Wc[k * D + m] * sWt[m * D + n];
            } else {
                f = W0[(k - D) * D + n] - sWt[(k - D) * D + n];
            }
            v[j] = f2bf(f);
        }
        *(uint4*)(Wp + (long)id * 8) = *(uint4*)v;
        return;
    }

    // xcast path
    const int gid = (blockIdx.x - 17) * 256 + t;  // 0 .. N*16-1
    const int node = gid >> 4;
    const int c = gid & 15;
    const float di = dinv[node];
    const float4 a = ((const float4*)x)[(long)node * 32 + c * 2];
    const float4 b = ((const float4*)x)[(long)node * 32 + c * 2 + 1];
    const float f[8] = {a.x, a.y, a.z, a.w, b.x, b.y, b.z, b.w};
    unsigned short vd[8], vb[8];
#pragma unroll
    for (int j = 0; j < 8; ++j) {
        vd[j] = f2bf(di * f[j]);
        vb[j] = f2bf(f[j]);
    }
    *(uint4*)(xd + (long)node * 128 + c * 8) = *(uint4*)vd;
    *(uint4*)(xb + (long)node * 128 + c * 8) = *(uint4*)vb;
}

// ---------------------------------------------------------------------------
// Fused gather + GEMM. Block = 4 waves; wave w owns rows row0..row0+15.
// Phase 1 (per wave): for each of its 16 nodes, gather
//   g[n] = dinv[n] * ( sum_e xd[src_e] + xd[n] )    into wave-private LDS (bf16).
// Phase 2: out[16x128] = mfma( A=[g | xb], Wp ) + bv.   No __syncthreads needed.
__global__ __launch_bounds__(256) void k_gmm(const unsigned short* __restrict__ xd,
                                             const unsigned short* __restrict__ xb,
                                             const int* __restrict__ row_start,
                                             const int* __restrict__ cnt,
                                             const int* __restrict__ esrc,
                                             const float* __restrict__ dinv,
                                             const unsigned short* __restrict__ Wp,
                                             const float* __restrict__ bv,
                                             float* __restrict__ out) {
    __shared__ unsigned short gl[4][16][GROWS];
    const int tid = threadIdx.x;
    const int wave = tid >> 6;
    const int lane = tid & 63;
    const int lr = lane & 15;   // gather: 16B chunk id; mm: A-row / C-col
    const int sl = lane >> 4;   // gather: edge slot 0..3; mm: quad
    const int row0 = blockIdx.x * 64 + wave * 16;

    // lanes 0..15 preload this wave's 16 nodes' CSR meta
    const int myrow = row0 + lr;
    int vbegin = 0, vcnt = 0;
    float vdinv = 0.f;
    if (lr < 16 && myrow < N_NODES) {
        vbegin = row_start[myrow];
        vcnt = cnt[myrow];
        vdinv = dinv[myrow];
    }

    for (int r = 0; r < 16; ++r) {
        const int node = row0 + r;
        const int begin = __shfl(vbegin, r);
        const int end = begin + __shfl(vcnt, r);
        float acc[8] = {};
        int i = begin + sl;
        for (; i + 4 < end; i += 8) {  // two edges in flight per slot
            const int a0 = esrc[i];
            const int a1 = esrc[i + 4];
            const short8 v0 = *(const short8*)(xd + (long)a0 * 128 + lr * 8);
            const short8 v1 = *(const short8*)(xd + (long)a1 * 128 + lr * 8);
#pragma unroll
            for (int j = 0; j < 8; ++j)
                acc[j] += bf2f((unsigned short)v0[j]) + bf2f((unsigned short)v1[j]);
        }
        if (i < end) {
            const int a0 = esrc[i];
            const short8 v0 = *(const short8*)(xd + (long)a0 * 128 + lr * 8);
#pragma unroll
            for (int j = 0; j < 8; ++j) acc[j] += bf2f((unsigned short)v0[j]);
        }
#pragma unroll
        for (int j = 0; j < 8; ++j) {
            acc[j] += __shfl_xor(acc[j], 16);
            acc[j] += __shfl_xor(acc[j], 32);
        }
        if (sl == 0) {
            const float di = __shfl(vdinv, r);
            const int nn = (node < N_NODES) ? node : 0;
            const short8 xs = *(const short8*)(xd + (long)nn * 128 + lr * 8);
            unsigned short o[8];
#pragma unroll
            for (int j = 0; j < 8; ++j)
                o[j] = f2bf(di * (acc[j] + bf2f((unsigned short)xs[j])));
            *(uint4*)(&gl[wave][r][lr * 8]) = *(uint4*)o;
        }
    }

    // ---- MFMA phase (wave-private LDS; lgkmcnt ordering suffices) ----
    int ar = row0 + lr;
    if (ar >= N_NODES) ar = N_NODES - 1;  // clamp loads; stores guarded

    f32x4 accm[8] = {};
#pragma unroll
    for (int s = 0; s < 4; ++s) {  // g-half from LDS
        const short8 a = *(const short8*)(&gl[wave][lr][s * 32 + sl * 8]);
#pragma unroll
        for (int t = 0; t < 8; ++t) {
            const short8 b = *(const short8*)(Wp + ((long)(s * 8 + t) * 64 + lane) * 8);
            accm[t] = __builtin_amdgcn_mfma_f32_16x16x32_bf16(a, b, accm[t], 0, 0, 0);
        }
    }
#pragma unroll
    for (int s = 4; s < 8; ++s) {  // x-half from global
        const short8 a = *(const short8*)(xb + (long)ar * 128 + (s - 4) * 32 + sl * 8);
#pragma unroll
        for (int t = 0; t < 8; ++t) {
            const short8 b = *(const short8*)(Wp + ((long)(s * 8 + t) * 64 + lane) * 8);
            accm[t] = __builtin_amdgcn_mfma_f32_16x16x32_bf16(a, b, accm[t], 0, 0, 0);
        }
    }

#pragma unroll
    for (int t = 0; t < 8; ++t) {
        const int col = t * 16 + lr;
        const float bvv = bv[col];
#pragma unroll
        for (int r = 0; r < 4; ++r) {
            const int row = row0 + sl * 4 + r;
            if (row < N_NODES) out[(long)row * D + col] = accm[t][r] + bvv;
        }
    }
}

// ---------------------------------------------------------------------------
extern "C" void kernel_launch(void* const* d_in, const int* in_sizes, int n_in,
                              void* d_out, int out_size, void* d_ws, size_t ws_size,
                              hipStream_t stream) {
    const float* x  = (const float*)d_in[0];
    const int*   ei = (const int*)d_in[1];  // [2, E] flat: row0=src, row1=dst
    const float* Wc = (const float*)d_in[2];
    const float* bc = (const float*)d_in[3];
    const float* W0 = (const float*)d_in[4];
    const float* Wt = (const float*)d_in[5];
    float* out = (float*)d_out;

    const int* src = ei;
    const int* dst = ei + N_EDGES;

    // workspace layout:
    //   xd bf16 [N*128] | xb bf16 [N*128] | cnt [N] | row_start [N] | dinv [N] |
    //   esrc [NB*CAPB] | pbuf [NB*CAPB] | bv f32 [D] | Wp bf16 [256*128] | gcur [NB]
    unsigned short* xd = (unsigned short*)d_ws;
    unsigned short* xb = xd + (size_t)N_NODES * 128;
    int*   cnt        = (int*)(xb + (size_t)N_NODES * 128);
    int*   row_start  = cnt + N_NODES;
    float* dinv       = (float*)(row_start + N_NODES);
    int*   esrc       = (int*)(dinv + N_NODES);
    unsigned int* pbuf = (unsigned int*)(esrc + (size_t)NB * CAPB);
    float* bv         = (float*)(pbuf + (size_t)NB * CAPB);
    unsigned short* Wp = (unsigned short*)(bv + D);
    int*   gcur       = (int*)(Wp + 256 * D);

    k_init<<<1, 256, 0, stream>>>(gcur);
    k_part1<<<P1_BLOCKS, 256, 0, stream>>>(src, dst, gcur, pbuf);
    k_part2<<<NB, 256, 0, stream>>>(pbuf, gcur, row_start, cnt, dinv, esrc);
    k_wx<<<17 + (N_NODES * 16) / 256, 256, 0, stream>>>(Wc, W0, Wt, bc, x, dinv,
                                                        Wp, bv, xd, xb);
    k_gmm<<<(N_NODES + 63) / 64, 256, 0, stream>>>(xd, xb, row_start, cnt, esrc,
                                                   dinv, Wp, bv, out);
}

// Round 9
// 178.406 us; speedup vs baseline: 10.2260x; 1.0563x over previous
//
#include <hip/hip_runtime.h>

#define N_NODES 50000
#define N_EDGES 800000
#define D 128
#define NB 196                 // buckets: bucket = dst >> 8, 256 nodes each
#define CAPB 8192              // fixed slots per bucket (mean 4082, ~64 sigma)
#define P1_BLOCKS 256
#define EPB ((N_EDGES + P1_BLOCKS - 1) / P1_BLOCKS)  // 3125 edges/block
#define CAP 64                 // LDS staging slots per bucket in part1

typedef __attribute__((ext_vector_type(8))) short short8;
typedef __attribute__((ext_vector_type(4))) float f32x4;

// round-to-nearest-even f32 -> bf16 (as ushort)
__device__ __forceinline__ unsigned short f2bf(float f) {
    unsigned int u = __builtin_bit_cast(unsigned int, f);
    u += 0x7FFFu + ((u >> 16) & 1u);
    return (unsigned short)(u >> 16);
}
__device__ __forceinline__ float bf2f(unsigned short h) {
    unsigned int u = ((unsigned int)h) << 16;
    return __builtin_bit_cast(float, u);
}

// ---------------------------------------------------------------------------
// gcur[b] = b * CAPB   (fixed bucket bases; no hist/scan/memset needed)
__global__ void k_init(int* __restrict__ gcur) {
    const int t = threadIdx.x;
    if (t < NB) gcur[t] = t * CAPB;
}

// Partition edges into fixed-base buckets with LDS write-combining.
// pbuf code: (local_dst << 16) | src   (src < 65536, local_dst < 256)
__global__ __launch_bounds__(256) void k_part1(const int* __restrict__ src,
                                               const int* __restrict__ dst,
                                               int* __restrict__ gcur,
                                               unsigned int* __restrict__ pbuf) {
    __shared__ unsigned int stage[NB][CAP + 1];  // +1 pad: drain reads conflict-free
    __shared__ int scnt[NB];
    const int t = threadIdx.x;
    for (int i = t; i < NB; i += 256) scnt[i] = 0;
    __syncthreads();

    const long e0 = (long)blockIdx.x * EPB;
    const long e1 = (e0 + EPB < N_EDGES) ? e0 + EPB : N_EDGES;
    for (long e = e0 + t; e < e1; e += 256) {
        const int s = src[e];
        const int d = dst[e];
        const int b = d >> 8;
        const unsigned int p = ((unsigned int)(d & 255) << 16) | (unsigned int)s;
        const int slot = atomicAdd(&scnt[b], 1);
        if (slot < CAP) {
            stage[b][slot] = p;
        } else {  // spill (statistically ~never; correctness for any distribution)
            const int pos = atomicAdd(&gcur[b], 1);
            pbuf[pos] = p;
        }
    }
    __syncthreads();
    // cooperative drain: thread t drains bucket t in one contiguous burst
    if (t < NB) {
        const int n = (scnt[t] < CAP) ? scnt[t] : CAP;
        if (n > 0) {
            const int pos = atomicAdd(&gcur[t], n);
            for (int i = 0; i < n; ++i) pbuf[pos + i] = stage[t][i];
        }
    }
}

// Per-bucket local CSR build: hist + scan in LDS, scatter into L2-local window.
// Produces row_start / cnt / dinv.
__global__ __launch_bounds__(256) void k_part2(const unsigned int* __restrict__ pbuf,
                                               const int* __restrict__ gcur,
                                               int* __restrict__ row_start,
                                               int* __restrict__ cnt,
                                               float* __restrict__ dinv,
                                               int* __restrict__ esrc) {
    __shared__ int lcnt[256];
    __shared__ int lcur[256];
    __shared__ int stmp[256];
    const int b = blockIdx.x;
    const int t = threadIdx.x;
    const int base = b * CAPB;
    const int n = gcur[b] - base;

    lcnt[t] = 0;
    __syncthreads();
    for (int i = t; i < n; i += 256) atomicAdd(&lcnt[pbuf[base + i] >> 16], 1);
    __syncthreads();

    const int c = lcnt[t];
    stmp[t] = c;
    __syncthreads();
    for (int off = 1; off < 256; off <<= 1) {
        int u = (t >= off) ? stmp[t - off] : 0;
        __syncthreads();
        stmp[t] += u;
        __syncthreads();
    }
    const int ls = base + stmp[t] - c;  // exclusive, within bucket window
    lcur[t] = ls;
    const int node = b * 256 + t;
    if (node < N_NODES) {
        row_start[node] = ls;
        cnt[node] = c;
        dinv[node] = rsqrtf((float)c + 1.0f);
    }
    __syncthreads();

    for (int i = t; i < n; i += 256) {
        const unsigned int p = pbuf[base + i];
        const int pos = atomicAdd(&lcur[p >> 16], 1);
        esrc[pos] = (int)(p & 0xFFFFu);
    }
}

// ---------------------------------------------------------------------------
// Fused weight-pack + x-cast.
// Blocks 0..15: pack Wab = [Wc + Wc@Wt ; W0 - Wt] (256x128) into bf16 B-fragment
// order for 16x16x32. Block 16: bv = bc + bc@Wt.
// Blocks 17..: xd[n] = bf16(dinv[n]*x[n]), gx[n][128:256] = bf16(x[n]).
__global__ __launch_bounds__(256) void k_wx(const float* __restrict__ Wc,
                                            const float* __restrict__ W0,
                                            const float* __restrict__ Wt,
                                            const float* __restrict__ bc,
                                            const float* __restrict__ x,
                                            const float* __restrict__ dinv,
                                            unsigned short* __restrict__ Wp,
                                            float* __restrict__ bv,
                                            unsigned short* __restrict__ xd,
                                            unsigned short* __restrict__ gx) {
    __shared__ float sWt[D * D];
    const int t = threadIdx.x;

    if (blockIdx.x < 17) {
        for (int i = t * 4; i < D * D; i += 256 * 4)
            *(float4*)(sWt + i) = *(const float4*)(Wt + i);
        __syncthreads();

        if (blockIdx.x == 16) {
            if (t < D) {
                float acc = bc[t];
#pragma unroll 16
                for (int k = 0; k < D; ++k) acc += bc[k] * sWt[k * D + t];
                bv[t] = acc;
            }
            return;
        }
        const int id = blockIdx.x * 256 + t;  // 0..4095
        const int lane = id & 63;
        const int tile = (id >> 6) & 7;
        const int step = id >> 9;
        const int n = tile * 16 + (lane & 15);
        const int kbase = step * 32 + (lane >> 4) * 8;
        unsigned short v[8];
#pragma unroll
        for (int j = 0; j < 8; ++j) {
            const int k = kbase + j;
            float f;
            if (k < D) {
                f = Wc[k * D + n];
#pragma unroll 16
                for (int m = 0; m < D; ++m) f += Wc[k * D + m] * sWt[m * D + n];
            } else {
                f = W0[(k - D) * D + n] - sWt[(k - D) * D + n];
            }
            v[j] = f2bf(f);
        }
        *(uint4*)(Wp + (long)id * 8) = *(uint4*)v;
        return;
    }

    // xcast path
    const int gid = (blockIdx.x - 17) * 256 + t;  // 0 .. N*16-1
    const int node = gid >> 4;
    const int c = gid & 15;
    const float di = dinv[node];
    const float4 a = ((const float4*)x)[(long)node * 32 + c * 2];
    const float4 b = ((const float4*)x)[(long)node * 32 + c * 2 + 1];
    const float f[8] = {a.x, a.y, a.z, a.w, b.x, b.y, b.z, b.w};
    unsigned short vd[8], vb[8];
#pragma unroll
    for (int j = 0; j < 8; ++j) {
        vd[j] = f2bf(di * f[j]);
        vb[j] = f2bf(f[j]);
    }
    *(uint4*)(xd + (long)node * 128 + c * 8) = *(uint4*)vd;
    *(uint4*)(gx + (long)node * 256 + 128 + c * 8) = *(uint4*)vb;
}

// ---------------------------------------------------------------------------
// Gather (bf16 rows): one 64-lane wave per node (4 nodes / block, 12500 blocks).
//   g[n] = dinv[n] * ( sum_e xd[src_e] + xd[n] )      (xd pre-scaled by dinv)
// Lane layout: c = lane&15 -> 8-elem chunk (16 B), s = lane>>4 -> edge slot 0..3.
// Unroll 4 per slot: 16 outstanding 16 B loads per wave.
__global__ __launch_bounds__(256) void k_gather(const unsigned short* __restrict__ xd,
                                                const int* __restrict__ row_start,
                                                const int* __restrict__ cnt,
                                                const int* __restrict__ esrc,
                                                const float* __restrict__ dinv,
                                                unsigned short* __restrict__ gx) {
    const int node = blockIdx.x * 4 + (threadIdx.x >> 6);
    const int lane = threadIdx.x & 63;
    const int c = lane & 15;
    const int s = lane >> 4;
    const int begin = row_start[node];
    const int end = begin + cnt[node];

    float acc[8] = {};
    int i = begin + s;
    for (; i + 12 < end; i += 16) {  // four edges in flight per slot
        const int a0 = esrc[i];
        const int a1 = esrc[i + 4];
        const int a2 = esrc[i + 8];
        const int a3 = esrc[i + 12];
        const short8 v0 = *(const short8*)(xd + (long)a0 * 128 + c * 8);
        const short8 v1 = *(const short8*)(xd + (long)a1 * 128 + c * 8);
        const short8 v2 = *(const short8*)(xd + (long)a2 * 128 + c * 8);
        const short8 v3 = *(const short8*)(xd + (long)a3 * 128 + c * 8);
#pragma unroll
        for (int j = 0; j < 8; ++j)
            acc[j] += (bf2f((unsigned short)v0[j]) + bf2f((unsigned short)v1[j])) +
                      (bf2f((unsigned short)v2[j]) + bf2f((unsigned short)v3[j]));
    }
    for (; i < end; i += 4) {
        const int a0 = esrc[i];
        const short8 v0 = *(const short8*)(xd + (long)a0 * 128 + c * 8);
#pragma unroll
        for (int j = 0; j < 8; ++j) acc[j] += bf2f((unsigned short)v0[j]);
    }

#pragma unroll
    for (int j = 0; j < 8; ++j) {
        acc[j] += __shfl_xor(acc[j], 16);
        acc[j] += __shfl_xor(acc[j], 32);
    }

    if (s == 0) {
        const float di = dinv[node];
        const short8 xs = *(const short8*)(xd + (long)node * 128 + c * 8);
        unsigned short o[8];
#pragma unroll
        for (int j = 0; j < 8; ++j)
            o[j] = f2bf(di * (acc[j] + bf2f((unsigned short)xs[j])));
        *(uint4*)(gx + (long)node * 256 + c * 8) = *(uint4*)o;
    }
}

// ---------------------------------------------------------------------------
// out[N,128] = bf16_gemm( gx[N,256], Wab[256,128] ) + bv
// 4 waves/block, each wave: 16 rows x 128 cols via 8 accumulators of 16x16x32.
__global__ __launch_bounds__(256) void k_mm(const unsigned short* __restrict__ gx,
                                            const unsigned short* __restrict__ Wp,
                                            const float* __restrict__ bv,
                                            float* __restrict__ out) {
    const int tid = threadIdx.x;
    const int wave = tid >> 6;
    const int lane = tid & 63;
    const int quad = lane >> 4;
    const int lr = lane & 15;
    const int row0 = blockIdx.x * 64 + wave * 16;

    int ar = row0 + lr;
    if (ar >= N_NODES) ar = N_NODES - 1;  // clamp loads; stores are guarded
    const unsigned short* aptr = gx + (long)ar * 256 + quad * 8;

    f32x4 acc[8] = {};

#pragma unroll
    for (int s = 0; s < 8; ++s) {
        const short8 a = *(const short8*)(aptr + s * 32);
#pragma unroll
        for (int t = 0; t < 8; ++t) {
            const short8 b = *(const short8*)(Wp + ((long)(s * 8 + t) * 64 + lane) * 8);
            acc[t] = __builtin_amdgcn_mfma_f32_16x16x32_bf16(a, b, acc[t], 0, 0, 0);
        }
    }

#pragma unroll
    for (int t = 0; t < 8; ++t) {
        const int col = t * 16 + lr;
        const float bvv = bv[col];
#pragma unroll
        for (int r = 0; r < 4; ++r) {
            const int row = row0 + quad * 4 + r;
            if (row < N_NODES) out[(long)row * D + col] = acc[t][r] + bvv;
        }
    }
}

// ---------------------------------------------------------------------------
extern "C" void kernel_launch(void* const* d_in, const int* in_sizes, int n_in,
                              void* d_out, int out_size, void* d_ws, size_t ws_size,
                              hipStream_t stream) {
    const float* x  = (const float*)d_in[0];
    const int*   ei = (const int*)d_in[1];  // [2, E] flat: row0=src, row1=dst
    const float* Wc = (const float*)d_in[2];
    const float* bc = (const float*)d_in[3];
    const float* W0 = (const float*)d_in[4];
    const float* Wt = (const float*)d_in[5];
    float* out = (float*)d_out;

    const int* src = ei;
    const int* dst = ei + N_EDGES;

    // workspace layout:
    //   xd bf16 [N*128] | gx bf16 [N*256] | cnt [N] | row_start [N] | dinv [N] |
    //   esrc [NB*CAPB] | pbuf [NB*CAPB] | bv f32 [D] | Wp bf16 [256*128] | gcur [NB]
    unsigned short* xd = (unsigned short*)d_ws;
    unsigned short* gx = xd + (size_t)N_NODES * 128;
    int*   cnt        = (int*)(gx + (size_t)N_NODES * 256);
    int*   row_start  = cnt + N_NODES;
    float* dinv       = (float*)(row_start + N_NODES);
    int*   esrc       = (int*)(dinv + N_NODES);
    unsigned int* pbuf = (unsigned int*)(esrc + (size_t)NB * CAPB);
    float* bv         = (float*)(pbuf + (size_t)NB * CAPB);
    unsigned short* Wp = (unsigned short*)(bv + D);
    int*   gcur       = (int*)(Wp + 256 * D);

    k_init<<<1, 256, 0, stream>>>(gcur);
    k_part1<<<P1_BLOCKS, 256, 0, stream>>>(src, dst, gcur, pbuf);
    k_part2<<<NB, 256, 0, stream>>>(pbuf, gcur, row_start, cnt, dinv, esrc);
    k_wx<<<17 + (N_NODES * 16) / 256, 256, 0, stream>>>(Wc, W0, Wt, bc, x, dinv,
                                                        Wp, bv, xd, gx);
    k_gather<<<N_NODES / 4, 256, 0, stream>>>(xd, row_start, cnt, esrc, dinv, gx);
    k_mm<<<(N_NODES + 63) / 64, 256, 0, stream>>>(gx, Wp, bv, out);
}